// Round 9
// baseline (4041.908 us; speedup 1.0000x reference)
//
#include <hip/hip_runtime.h>
#include <math.h>

#define M_TOTAL 2048
#define N_TOTAL 1024
#define TSEQ    80
#define EMB_D   512
#define VOCAB   50000
#define EW_ROWS 50176            // VOCAB padded to 256
#define BK      64

typedef __attribute__((ext_vector_type(8))) short bf16x8;
typedef __attribute__((ext_vector_type(4))) float f32x4;

__device__ __forceinline__ ushort f2bf(float f) {
    union { float f; unsigned u; } v; v.f = f;
    unsigned r = v.u + 0x7FFFu + ((v.u >> 16) & 1u);
    return (ushort)(r >> 16);
}
__device__ __forceinline__ float bf2f(ushort h) {
    union { unsigned u; float f; } v; v.u = ((unsigned)h) << 16;
    return v.f;
}
__device__ __forceinline__ void gload_lds16(const ushort* g, ushort* l) {
    __builtin_amdgcn_global_load_lds(
        (const __attribute__((address_space(1))) void*)g,
        (__attribute__((address_space(3))) void*)l, 16, 0, 0);
}
#define VMC6()  asm volatile("s_waitcnt vmcnt(6)" ::: "memory")
#define VMC0()  asm volatile("s_waitcnt vmcnt(0)" ::: "memory")
#define SBAR()  __builtin_amdgcn_s_barrier()
#define SCHED0() __builtin_amdgcn_sched_barrier(0)

// ---------------------------------------------------------------------------
// GEMM core: 256x128 tile, 512 thr (8 waves 4x2, wave-tile 64x64).
// Depth-3 LDS ring for A (256x64 chunks, 32 KB) and B (128x64, 16 KB):
// 144 KB LDS total -> deliberately 1 block/CU, latency hidden by the ring.
// Per chunk/thread: 4 A-loads + 2 B-loads = 6; steady wait vmcnt(6) keeps
// chunk c+1 in flight across the barrier (prefetch distance 2 chunks).
// ---------------------------------------------------------------------------
template<int NC>
__device__ __forceinline__ void gemm_core(
    f32x4 (&acc)[4][4],
    const ushort* __restrict__ A, const size_t* __restrict__ ga,
    const ushort* __restrict__ B, const size_t* __restrict__ gb,
    int w, int l,
    ushort (*As)[256 * BK], ushort (*Bs)[128 * BK])
{
    const int wr = w >> 1, wc = w & 1;
    auto stage = [&](int c, int buf) {
        const int k0 = c << 6;
        #pragma unroll
        for (int j = 0; j < 4; ++j)      // A: wave w stages rows w*32..+31
            gload_lds16(A + ga[j] + k0, &As[buf][(w * 32 + j * 8) * BK + l * 8]);
        #pragma unroll
        for (int j = 0; j < 2; ++j)      // B: wave w stages rows w*16..+15
            gload_lds16(B + gb[j] + k0, &Bs[buf][(w * 16 + j * 8) * BK + l * 8]);
    };
    stage(0, 0);
    stage(1, 1);
    #pragma unroll
    for (int c = 0; c < NC; ++c) {
        if (c + 1 < NC) { VMC6(); } else { VMC0(); }
        SBAR(); SCHED0();
        if (c + 2 < NC) stage(c + 2, (c + 2) % 3);
        const int buf = c % 3;
        #pragma unroll
        for (int kf = 0; kf < 2; ++kf) {
            const int ke = kf * 32 + (l >> 4) * 8;
            bf16x8 a[4], b[4];
            #pragma unroll
            for (int mf = 0; mf < 4; ++mf) {
                const int row = wr * 64 + mf * 16 + (l & 15);
                a[mf] = *(const bf16x8*)&As[buf][row * BK + (ke ^ ((row & 7) << 3))];
            }
            #pragma unroll
            for (int nf = 0; nf < 4; ++nf) {
                const int row = wc * 64 + nf * 16 + (l & 15);
                b[nf] = *(const bf16x8*)&Bs[buf][row * BK + (ke ^ ((row & 7) << 3))];
            }
            #pragma unroll
            for (int mf = 0; mf < 4; ++mf)
                #pragma unroll
                for (int nf = 0; nf < 4; ++nf)
                    acc[mf][nf] = __builtin_amdgcn_mfma_f32_16x16x32_bf16(
                        a[mf], b[nf], acc[mf][nf], 0, 0, 0);
        }
    }
}

// ---------------------------------------------------------------------------
// Fused per-step kernel, grid 256 (exactly 1 block/CU, one residency round):
//   n = bid&7  (XCD-pinned 128-col weight strip; N/128 == 8 == #XCDs)
//   rest = bid>>3:  0..7  J1  m=rest      h1[i]   = tanh(xw1[i]+h1[i-1]@U1+b1)
//                   8..15 J2  m=rest-8    xw2[i-1]= h1[i-1]@W2   (fp32 store)
//                  16..23 J3  m=rest-16   h2[i-2] = tanh(xw2[i-2]+h2[i-3]@U2+b2)
//                  24..31 J0  gather xw1[i+1] rows of EW1 -> sl_next
// ---------------------------------------------------------------------------
__global__ __launch_bounds__(512, 1) void fused_step(
    const ushort* __restrict__ EW1,
    const int* __restrict__ tok,
    const ushort* __restrict__ sl_prev,   // h1[i-1] (h1zero at i==0)
    ushort* __restrict__ sl_cur,          // xw1[i] -> h1[i] (in place)
    ushort* __restrict__ sl_next,         // J0 dst: xw1[i+1]
    const ushort* __restrict__ U1T, const float* __restrict__ b1,
    const ushort* __restrict__ W2T,
    float* __restrict__ xw2_dst,
    const float* __restrict__ xw2_src,
    const ushort* __restrict__ U2T, const float* __restrict__ b2,
    const ushort* __restrict__ h2prev,
    ushort* __restrict__ h2dst,
    int i)
{
    __shared__ ushort As[3][256 * BK];   // 96 KB
    __shared__ ushort Bs[3][128 * BK];   // 48 KB
    const int tid = threadIdx.x;
    const int bid = blockIdx.x;
    const int n = bid & 7, rest = bid >> 3;

    if (rest >= 24) {                    // ---- J0: gather xw1[i+1]
        if (i > TSEQ - 2) return;
        const int base = (rest - 24) * 256;          // 256 rows per block
        #pragma unroll
        for (int p = 0; p < 4; ++p) {
            const int b = base + p * 64 + (tid >> 3);
            const int token = tok[b * TSEQ + i + 1];
            const uint4* src = (const uint4*)(EW1 + (size_t)token * N_TOTAL);
            uint4* dst = (uint4*)(sl_next + (size_t)b * N_TOTAL);
            #pragma unroll
            for (int g = 0; g < 16; ++g)
                dst[(tid & 7) + g * 8] = src[(tid & 7) + g * 8];
        }
        return;
    }

    const int w = tid >> 6, l = tid & 63;
    const int job = rest >> 3;           // 0,1,2
    const int m = rest & 7;
    const int bm0 = m << 8, bn0 = n << 7;

    if (job == 0 && i > TSEQ - 1) return;
    if (job == 1 && (i < 1 || i > TSEQ)) return;
    if (job == 2 && i < 2) return;

    const ushort* A; const ushort* B;
    if (job == 0)      { A = sl_prev; B = U1T; }
    else if (job == 1) { A = sl_prev; B = W2T; }
    else               { A = h2prev;  B = U2T; }

    const int lr = l >> 3;
    const int se = ((l & 7) ^ lr) << 3;
    size_t ga[4], gb[2];
    #pragma unroll
    for (int j = 0; j < 4; ++j)
        ga[j] = (size_t)(bm0 + w * 32 + j * 8 + lr) * N_TOTAL + se;
    #pragma unroll
    for (int j = 0; j < 2; ++j)
        gb[j] = (size_t)(bn0 + w * 16 + j * 8 + lr) * N_TOTAL + se;

    f32x4 acc[4][4] = {};
    gemm_core<16>(acc, A, ga, B, gb, w, l, As, Bs);

    const int wr = w >> 1, wc = w & 1;
    #pragma unroll
    for (int nf = 0; nf < 4; ++nf) {
        const int col = bn0 + wc * 64 + nf * 16 + (l & 15);
        #pragma unroll
        for (int mf = 0; mf < 4; ++mf) {
            const int rb = bm0 + wr * 64 + mf * 16 + (l >> 4) * 4;
            #pragma unroll
            for (int r = 0; r < 4; ++r) {
                const size_t idx = (size_t)(rb + r) * N_TOTAL + col;
                if (job == 0)
                    sl_cur[idx] = f2bf(tanhf(acc[mf][nf][r] + bf2f(sl_cur[idx]) + b1[col]));
                else if (job == 1)
                    xw2_dst[idx] = acc[mf][nf][r];
                else
                    h2dst[idx] = f2bf(tanhf(acc[mf][nf][r] + xw2_src[idx] + b2[col]));
            }
        }
    }
}

// ---------------------------------------------------------------------------
// EW1[v][n] = embb[v] @ W1^T  (one-time, M=50176 padded, K=512, NC=8)
// ---------------------------------------------------------------------------
__global__ __launch_bounds__(512, 1) void ew1_gemm(
    ushort* __restrict__ EW1,
    const ushort* __restrict__ embb,     // [50000][512]
    const ushort* __restrict__ W1T)      // [1024][512]
{
    __shared__ ushort As[3][256 * BK];
    __shared__ ushort Bs[3][128 * BK];
    const int tid = threadIdx.x;
    const int w = tid >> 6, l = tid & 63;
    const int bid = blockIdx.x;
    const int n = bid & 7, m = bid >> 3;        // m 0..195
    const int bm0 = m << 8, bn0 = n << 7;

    const int lr = l >> 3;
    const int se = ((l & 7) ^ lr) << 3;
    size_t ga[4], gb[2];
    #pragma unroll
    for (int j = 0; j < 4; ++j) {
        int row = bm0 + w * 32 + j * 8 + lr;
        if (row >= VOCAB) row = VOCAB - 1;      // clamp (results discarded)
        ga[j] = (size_t)row * EMB_D + se;
    }
    #pragma unroll
    for (int j = 0; j < 2; ++j)
        gb[j] = (size_t)(bn0 + w * 16 + j * 8 + lr) * EMB_D + se;

    f32x4 acc[4][4] = {};
    gemm_core<8>(acc, embb, ga, W1T, gb, w, l, As, Bs);

    const int wr = w >> 1, wc = w & 1;
    #pragma unroll
    for (int nf = 0; nf < 4; ++nf) {
        const int col = bn0 + wc * 64 + nf * 16 + (l & 15);
        #pragma unroll
        for (int mf = 0; mf < 4; ++mf) {
            const int rb = bm0 + wr * 64 + mf * 16 + (l >> 4) * 4;
            #pragma unroll
            for (int r = 0; r < 4; ++r)
                if (rb + r < VOCAB)
                    EW1[(size_t)(rb + r) * N_TOTAL + col] = f2bf(acc[mf][nf][r]);
        }
    }
}

// gather xw1[0] into ring slab (prologue)
__global__ __launch_bounds__(256) void gather_xw1(
    ushort* __restrict__ dst, const ushort* __restrict__ EW1,
    const int* __restrict__ tok, int t)
{
    const int b = blockIdx.x * 32 + (threadIdx.x >> 3);
    const int token = tok[b * TSEQ + t];
    const uint4* src = (const uint4*)(EW1 + (size_t)token * N_TOTAL);
    uint4* d = (uint4*)(dst + (size_t)b * N_TOTAL);
    #pragma unroll
    for (int g = 0; g < 16; ++g)
        d[(threadIdx.x & 7) + g * 8] = src[(threadIdx.x & 7) + g * 8];
}

// emb fp32 -> bf16 (50000*512/8/256 = 12500 blocks)
__global__ __launch_bounds__(256) void emb_convert(
    ushort* __restrict__ dst, const float* __restrict__ src)
{
    const size_t i = ((size_t)blockIdx.x * 256 + threadIdx.x) * 8;
    const float4 v0 = *(const float4*)(src + i);
    const float4 v1 = *(const float4*)(src + i + 4);
    const unsigned w0 = f2bf(v0.x) | (f2bf(v0.y) << 16);
    const unsigned w1 = f2bf(v0.z) | (f2bf(v0.w) << 16);
    const unsigned w2 = f2bf(v1.x) | (f2bf(v1.y) << 16);
    const unsigned w3 = f2bf(v1.z) | (f2bf(v1.w) << 16);
    *(uint4*)(dst + i) = make_uint4(w0, w1, w2, w3);
}

// W [K][N] fp32 -> WT [N][K] bf16
__global__ __launch_bounds__(256) void transpose_convert(
    ushort* __restrict__ outT, const float* __restrict__ in, int K, int N)
{
    __shared__ float tile[64][65];
    const int tiles_n = N >> 6;
    const int k0 = (blockIdx.x / tiles_n) << 6;
    const int n0 = (blockIdx.x % tiles_n) << 6;
    const int tid = threadIdx.x;
    const int r = tid >> 4, c = (tid & 15) << 2;
    #pragma unroll
    for (int i = 0; i < 4; ++i) {
        const float4 v = *(const float4*)(in + (size_t)(k0 + r + i * 16) * N + n0 + c);
        tile[r + i * 16][c + 0] = v.x;
        tile[r + i * 16][c + 1] = v.y;
        tile[r + i * 16][c + 2] = v.z;
        tile[r + i * 16][c + 3] = v.w;
    }
    __syncthreads();
    const int n = tid >> 2, ks = (tid & 3) << 4;
    unsigned pk[8];
    #pragma unroll
    for (int j = 0; j < 8; ++j) {
        const unsigned lo = f2bf(tile[ks + 2 * j][n]);
        const unsigned hi = f2bf(tile[ks + 2 * j + 1][n]);
        pk[j] = lo | (hi << 16);
    }
    ushort* dst = outT + (size_t)(n0 + n) * K + k0 + ks;
    *(uint4*)(dst + 0) = make_uint4(pk[0], pk[1], pk[2], pk[3]);
    *(uint4*)(dst + 8) = make_uint4(pk[4], pk[5], pk[6], pk[7]);
}

__global__ __launch_bounds__(256) void out_kernel(
    float* __restrict__ out, const ushort* __restrict__ h2,
    const float* __restrict__ Wo, const float* __restrict__ bo)
{
    const int row  = blockIdx.x * 4 + (threadIdx.x >> 6);
    const int lane = threadIdx.x & 63;
    const ushort* hr = h2 + (size_t)row * N_TOTAL;
    float s = 0.f;
    for (int k = lane; k < N_TOTAL; k += 64)
        s += bf2f(hr[k]) * Wo[k];
    #pragma unroll
    for (int off = 32; off; off >>= 1)
        s += __shfl_down(s, off);
    if (lane == 0)
        out[row] = 1.f / (1.f + expf(-(s + bo[0])));
}

extern "C" void kernel_launch(void* const* d_in, const int* in_sizes, int n_in,
                              void* d_out, int out_size, void* d_ws, size_t ws_size,
                              hipStream_t stream) {
    const int*   tokens = (const int*)  d_in[0];
    const float* emb    = (const float*)d_in[1];
    const float* W1     = (const float*)d_in[2];
    const float* U1     = (const float*)d_in[3];
    const float* b1     = (const float*)d_in[4];
    const float* W2     = (const float*)d_in[5];
    const float* U2     = (const float*)d_in[6];
    const float* b2     = (const float*)d_in[7];
    const float* Wo     = (const float*)d_in[8];
    const float* bo     = (const float*)d_in[9];
    float* out = (float*)d_out;

    char* ws = (char*)d_ws;
    const size_t HB = (size_t)M_TOTAL * N_TOTAL * sizeof(ushort);      // 4 MB
    size_t off = 0;
    ushort* h1zero = (ushort*)(ws + off); off += HB;
    ushort* h2x0   = (ushort*)(ws + off); off += HB;
    ushort* h2x1   = (ushort*)(ws + off); off += HB;
    ushort* ring0  = (ushort*)(ws + off); off += HB;
    ushort* ring1  = (ushort*)(ws + off); off += HB;
    ushort* ring2  = (ushort*)(ws + off); off += HB;
    float*  xw2f0  = (float*)(ws + off);  off += (size_t)M_TOTAL * N_TOTAL * 4;
    float*  xw2f1  = (float*)(ws + off);  off += (size_t)M_TOTAL * N_TOTAL * 4;
    ushort* W1T = (ushort*)(ws + off); off += (size_t)N_TOTAL * EMB_D   * 2;
    ushort* U1T = (ushort*)(ws + off); off += (size_t)N_TOTAL * N_TOTAL * 2;
    ushort* W2T = (ushort*)(ws + off); off += (size_t)N_TOTAL * N_TOTAL * 2;
    ushort* U2T = (ushort*)(ws + off); off += (size_t)N_TOTAL * N_TOTAL * 2;
    ushort* embb = (ushort*)(ws + off); off += (size_t)VOCAB * EMB_D * 2;
    ushort* EW1  = (ushort*)(ws + off); off += (size_t)EW_ROWS * N_TOTAL * 2;

    ushort* ring[3] = { ring0, ring1, ring2 };
    float*  xw2f[2] = { xw2f0, xw2f1 };
    ushort* h2x[2]  = { h2x0, h2x1 };

    hipMemsetAsync(h1zero, 0, HB, stream);
    hipMemsetAsync(h2x1,   0, HB, stream);   // h2[-1] zeros (read at i==2)

    emb_convert<<<dim3(12500), 256, 0, stream>>>(embb, emb);
    transpose_convert<<<dim3((EMB_D  / 64) * (N_TOTAL / 64)), 256, 0, stream>>>(W1T, W1, EMB_D,   N_TOTAL);
    transpose_convert<<<dim3((N_TOTAL / 64) * (N_TOTAL / 64)), 256, 0, stream>>>(U1T, U1, N_TOTAL, N_TOTAL);
    transpose_convert<<<dim3((N_TOTAL / 64) * (N_TOTAL / 64)), 256, 0, stream>>>(W2T, W2, N_TOTAL, N_TOTAL);
    transpose_convert<<<dim3((N_TOTAL / 64) * (N_TOTAL / 64)), 256, 0, stream>>>(U2T, U2, N_TOTAL, N_TOTAL);

    ew1_gemm<<<dim3((EW_ROWS / 256) * 8), 512, 0, stream>>>(EW1, embb, W1T);
    gather_xw1<<<dim3(64), 256, 0, stream>>>(ring[0], EW1, tokens, 0);

    for (int i = 0; i <= TSEQ + 1; ++i) {
        const ushort* sl_prev = (i == 0) ? h1zero : ring[(i - 1) % 3];
        ushort* sl_cur  = ring[i % 3];
        ushort* sl_next = ring[(i + 1) % 3];
        float* xw2_dst  = xw2f[(i - 1) & 1];
        const float* xw2_src = xw2f[(i - 2) & 1];
        const ushort* h2prev = h2x[(i - 3) & 1];
        ushort* h2dst = h2x[(i - 2) & 1];
        fused_step<<<dim3(256), 512, 0, stream>>>(
            EW1, tokens, sl_prev, sl_cur, sl_next,
            U1T, b1, W2T, xw2_dst, xw2_src, U2T, b2, h2prev, h2dst, i);
    }

    out_kernel<<<dim3(M_TOTAL / 4), dim3(256), 0, stream>>>(out, h2x[1], Wo, bo);
}

// Round 10
// 3792.215 us; speedup vs baseline: 1.0658x; 1.0658x over previous
//
#include <hip/hip_runtime.h>
#include <math.h>

#define M_TOTAL 2048
#define N_TOTAL 1024
#define TSEQ    80
#define EMB_D   512
#define VOCAB   50000
#define EW_ROWS 50048            // VOCAB padded to 128
#define BK      64

typedef __attribute__((ext_vector_type(8))) short bf16x8;
typedef __attribute__((ext_vector_type(4))) float f32x4;

__device__ __forceinline__ ushort f2bf(float f) {
    union { float f; unsigned u; } v; v.f = f;
    unsigned r = v.u + 0x7FFFu + ((v.u >> 16) & 1u);
    return (ushort)(r >> 16);
}
__device__ __forceinline__ float bf2f(ushort h) {
    union { unsigned u; float f; } v; v.u = ((unsigned)h) << 16;
    return v.f;
}
__device__ __forceinline__ void gload_lds16(const ushort* g, ushort* l) {
    __builtin_amdgcn_global_load_lds(
        (const __attribute__((address_space(1))) void*)g,
        (__attribute__((address_space(3))) void*)l, 16, 0, 0);
}
#define VM0()   asm volatile("s_waitcnt vmcnt(0)" ::: "memory")

// ---------------------------------------------------------------------------
// GEMM core: 128x128 tile, 256 thr (4 waves 2x2, wave-tile 64x64).
// Double-buffered A+B (64 KB LDS -> safe 2 blocks/CU). T3-minimum schedule:
//   per chunk: stage(c+1) ; compute(c) ; vmcnt(0) ; barrier
// stage(c+1) writes the buffer compute(c-1) finished with (prior barrier
// guarantees), and its latency hides under compute(c). 8 loads/thr/chunk.
// Wave-tile 64x64 minimizes LDS read amplification (4 B per output elem).
// ---------------------------------------------------------------------------
template<int NC>
__device__ __forceinline__ void gemm_core(
    f32x4 (&acc)[4][4],
    const ushort* __restrict__ A, const size_t* __restrict__ ga,
    const ushort* __restrict__ B, const size_t* __restrict__ gb,
    int w, int l,
    ushort (*As)[128 * BK], ushort (*Bs)[128 * BK])
{
    const int wr = w >> 1, wc = w & 1;
    auto stage = [&](int c, int buf) {
        const int k0 = c << 6;
        #pragma unroll
        for (int j = 0; j < 4; ++j)      // A: wave w stages rows w*32..+31
            gload_lds16(A + ga[j] + k0, &As[buf][(w * 32 + j * 8) * BK + l * 8]);
        #pragma unroll
        for (int j = 0; j < 4; ++j)      // B: wave w stages rows w*32..+31
            gload_lds16(B + gb[j] + k0, &Bs[buf][(w * 32 + j * 8) * BK + l * 8]);
    };
    stage(0, 0);
    VM0(); __syncthreads();
    #pragma unroll
    for (int c = 0; c < NC; ++c) {
        const int buf = c & 1;
        if (c + 1 < NC) stage(c + 1, buf ^ 1);
        #pragma unroll
        for (int kf = 0; kf < 2; ++kf) {
            const int ke = kf * 32 + (l >> 4) * 8;
            bf16x8 a[4], b[4];
            #pragma unroll
            for (int mf = 0; mf < 4; ++mf) {
                const int row = wr * 64 + mf * 16 + (l & 15);
                a[mf] = *(const bf16x8*)&As[buf][row * BK + (ke ^ ((row & 7) << 3))];
            }
            #pragma unroll
            for (int nf = 0; nf < 4; ++nf) {
                const int row = wc * 64 + nf * 16 + (l & 15);
                b[nf] = *(const bf16x8*)&Bs[buf][row * BK + (ke ^ ((row & 7) << 3))];
            }
            #pragma unroll
            for (int mf = 0; mf < 4; ++mf)
                #pragma unroll
                for (int nf = 0; nf < 4; ++nf)
                    acc[mf][nf] = __builtin_amdgcn_mfma_f32_16x16x32_bf16(
                        a[mf], b[nf], acc[mf][nf], 0, 0, 0);
        }
        VM0(); __syncthreads();
    }
}

// ---------------------------------------------------------------------------
// Fused per-step kernel, grid 448 (single residency round at 2 blocks/CU):
//   bid < 384 : GEMM. n = bid&7 (XCD-pinned 128-col weight strip),
//               rest = bid>>3 in 0..47, job = rest>>4, m = rest&15.
//     job0 (J1): h1[i]   = tanh(xw1[i] + h1[i-1]@U1 + b1)   [in-place slab]
//     job1 (J2): xw2[i-1]= h1[i-1]@W2                       [fp32 raw store]
//     job2 (J3): h2[i-2] = tanh(xw2[i-2] + h2[i-3]@U2 + b2)
//   bid 384..447 : J0 gather xw1[i+1] rows of EW1 -> sl_next (32 rows/block)
// ---------------------------------------------------------------------------
__global__ __launch_bounds__(256, 2) void fused_step(
    const ushort* __restrict__ EW1,
    const int* __restrict__ tok,
    const ushort* __restrict__ sl_prev,   // h1[i-1] (h1zero at i==0)
    ushort* __restrict__ sl_cur,          // xw1[i] -> h1[i] (in place)
    ushort* __restrict__ sl_next,         // J0 dst: xw1[i+1]
    const ushort* __restrict__ U1T, const float* __restrict__ b1,
    const ushort* __restrict__ W2T,
    float* __restrict__ xw2_dst,
    const float* __restrict__ xw2_src,
    const ushort* __restrict__ U2T, const float* __restrict__ b2,
    const ushort* __restrict__ h2prev,
    ushort* __restrict__ h2dst,
    int i)
{
    __shared__ ushort As[2][128 * BK];   // 32 KB
    __shared__ ushort Bs[2][128 * BK];   // 32 KB
    const int tid = threadIdx.x;
    const int bid = blockIdx.x;

    if (bid >= 384) {                    // ---- J0: gather xw1[i+1]
        if (i > TSEQ - 2) return;
        const int b = (bid - 384) * 32 + (tid >> 3);
        const int token = tok[b * TSEQ + i + 1];
        const uint4* src = (const uint4*)(EW1 + (size_t)token * N_TOTAL);
        uint4* dst = (uint4*)(sl_next + (size_t)b * N_TOTAL);
        #pragma unroll
        for (int g = 0; g < 16; ++g)
            dst[(tid & 7) + g * 8] = src[(tid & 7) + g * 8];
        return;
    }

    const int w = tid >> 6, l = tid & 63;
    const int n = bid & 7, rest = bid >> 3;
    const int job = rest >> 4;           // 0,1,2
    const int m = rest & 15;
    const int bm0 = m << 7, bn0 = n << 7;

    if (job == 0 && i > TSEQ - 1) return;
    if (job == 1 && (i < 1 || i > TSEQ)) return;
    if (job == 2 && i < 2) return;

    const ushort* A; const ushort* B;
    if (job == 0)      { A = sl_prev; B = U1T; }
    else if (job == 1) { A = sl_prev; B = W2T; }
    else               { A = h2prev;  B = U2T; }

    const int lr = l >> 3;
    const int se = ((l & 7) ^ lr) << 3;
    size_t ga[4], gb[4];
    #pragma unroll
    for (int j = 0; j < 4; ++j) {
        ga[j] = (size_t)(bm0 + w * 32 + j * 8 + lr) * N_TOTAL + se;
        gb[j] = (size_t)(bn0 + w * 32 + j * 8 + lr) * N_TOTAL + se;
    }

    f32x4 acc[4][4] = {};
    gemm_core<16>(acc, A, ga, B, gb, w, l, As, Bs);

    const int wr = w >> 1, wc = w & 1;
    #pragma unroll
    for (int nf = 0; nf < 4; ++nf) {
        const int col = bn0 + wc * 64 + nf * 16 + (l & 15);
        #pragma unroll
        for (int mf = 0; mf < 4; ++mf) {
            const int rb = bm0 + wr * 64 + mf * 16 + (l >> 4) * 4;
            #pragma unroll
            for (int r = 0; r < 4; ++r) {
                const size_t idx = (size_t)(rb + r) * N_TOTAL + col;
                if (job == 0)
                    sl_cur[idx] = f2bf(tanhf(acc[mf][nf][r] + bf2f(sl_cur[idx]) + b1[col]));
                else if (job == 1)
                    xw2_dst[idx] = acc[mf][nf][r];
                else
                    h2dst[idx] = f2bf(tanhf(acc[mf][nf][r] + xw2_src[idx] + b2[col]));
            }
        }
    }
}

// ---------------------------------------------------------------------------
// EW1[v][n] = embb[v] @ W1^T  (one-time, M=50048 padded, K=512, NC=8)
// ---------------------------------------------------------------------------
__global__ __launch_bounds__(256, 2) void ew1_gemm(
    ushort* __restrict__ EW1,
    const ushort* __restrict__ embb,     // [50000][512]
    const ushort* __restrict__ W1T)      // [1024][512]
{
    __shared__ ushort As[2][128 * BK];
    __shared__ ushort Bs[2][128 * BK];
    const int tid = threadIdx.x;
    const int w = tid >> 6, l = tid & 63;
    const int bid = blockIdx.x;
    const int n = bid & 7, m = bid >> 3;        // m 0..390
    const int bm0 = m << 7, bn0 = n << 7;

    const int lr = l >> 3;
    const int se = ((l & 7) ^ lr) << 3;
    size_t ga[4], gb[4];
    #pragma unroll
    for (int j = 0; j < 4; ++j) {
        int row = bm0 + w * 32 + j * 8 + lr;
        if (row >= VOCAB) row = VOCAB - 1;      // clamp (results discarded)
        ga[j] = (size_t)row * EMB_D + se;
        gb[j] = (size_t)(bn0 + w * 32 + j * 8 + lr) * EMB_D + se;
    }

    f32x4 acc[4][4] = {};
    gemm_core<8>(acc, embb, ga, W1T, gb, w, l, As, Bs);

    const int wr = w >> 1, wc = w & 1;
    #pragma unroll
    for (int nf = 0; nf < 4; ++nf) {
        const int col = bn0 + wc * 64 + nf * 16 + (l & 15);
        #pragma unroll
        for (int mf = 0; mf < 4; ++mf) {
            const int rb = bm0 + wr * 64 + mf * 16 + (l >> 4) * 4;
            #pragma unroll
            for (int r = 0; r < 4; ++r)
                if (rb + r < VOCAB)
                    EW1[(size_t)(rb + r) * N_TOTAL + col] = f2bf(acc[mf][nf][r]);
        }
    }
}

// gather xw1[0] into ring slab (prologue)
__global__ __launch_bounds__(256) void gather_xw1(
    ushort* __restrict__ dst, const ushort* __restrict__ EW1,
    const int* __restrict__ tok, int t)
{
    const int b = blockIdx.x * 32 + (threadIdx.x >> 3);
    const int token = tok[b * TSEQ + t];
    const uint4* src = (const uint4*)(EW1 + (size_t)token * N_TOTAL);
    uint4* d = (uint4*)(dst + (size_t)b * N_TOTAL);
    #pragma unroll
    for (int g = 0; g < 16; ++g)
        d[(threadIdx.x & 7) + g * 8] = src[(threadIdx.x & 7) + g * 8];
}

// emb fp32 -> bf16 (50000*512/8/256 = 12500 blocks)
__global__ __launch_bounds__(256) void emb_convert(
    ushort* __restrict__ dst, const float* __restrict__ src)
{
    const size_t i = ((size_t)blockIdx.x * 256 + threadIdx.x) * 8;
    const float4 v0 = *(const float4*)(src + i);
    const float4 v1 = *(const float4*)(src + i + 4);
    const unsigned w0 = f2bf(v0.x) | (f2bf(v0.y) << 16);
    const unsigned w1 = f2bf(v0.z) | (f2bf(v0.w) << 16);
    const unsigned w2 = f2bf(v1.x) | (f2bf(v1.y) << 16);
    const unsigned w3 = f2bf(v1.z) | (f2bf(v1.w) << 16);
    *(uint4*)(dst + i) = make_uint4(w0, w1, w2, w3);
}

// W [K][N] fp32 -> WT [N][K] bf16
__global__ __launch_bounds__(256) void transpose_convert(
    ushort* __restrict__ outT, const float* __restrict__ in, int K, int N)
{
    __shared__ float tile[64][65];
    const int tiles_n = N >> 6;
    const int k0 = (blockIdx.x / tiles_n) << 6;
    const int n0 = (blockIdx.x % tiles_n) << 6;
    const int tid = threadIdx.x;
    const int r = tid >> 4, c = (tid & 15) << 2;
    #pragma unroll
    for (int i = 0; i < 4; ++i) {
        const float4 v = *(const float4*)(in + (size_t)(k0 + r + i * 16) * N + n0 + c);
        tile[r + i * 16][c + 0] = v.x;
        tile[r + i * 16][c + 1] = v.y;
        tile[r + i * 16][c + 2] = v.z;
        tile[r + i * 16][c + 3] = v.w;
    }
    __syncthreads();
    const int n = tid >> 2, ks = (tid & 3) << 4;
    unsigned pk[8];
    #pragma unroll
    for (int j = 0; j < 8; ++j) {
        const unsigned lo = f2bf(tile[ks + 2 * j][n]);
        const unsigned hi = f2bf(tile[ks + 2 * j + 1][n]);
        pk[j] = lo | (hi << 16);
    }
    ushort* dst = outT + (size_t)(n0 + n) * K + k0 + ks;
    *(uint4*)(dst + 0) = make_uint4(pk[0], pk[1], pk[2], pk[3]);
    *(uint4*)(dst + 8) = make_uint4(pk[4], pk[5], pk[6], pk[7]);
}

__global__ __launch_bounds__(256) void out_kernel(
    float* __restrict__ out, const ushort* __restrict__ h2,
    const float* __restrict__ Wo, const float* __restrict__ bo)
{
    const int row  = blockIdx.x * 4 + (threadIdx.x >> 6);
    const int lane = threadIdx.x & 63;
    const ushort* hr = h2 + (size_t)row * N_TOTAL;
    float s = 0.f;
    for (int k = lane; k < N_TOTAL; k += 64)
        s += bf2f(hr[k]) * Wo[k];
    #pragma unroll
    for (int off = 32; off; off >>= 1)
        s += __shfl_down(s, off);
    if (lane == 0)
        out[row] = 1.f / (1.f + expf(-(s + bo[0])));
}

extern "C" void kernel_launch(void* const* d_in, const int* in_sizes, int n_in,
                              void* d_out, int out_size, void* d_ws, size_t ws_size,
                              hipStream_t stream) {
    const int*   tokens = (const int*)  d_in[0];
    const float* emb    = (const float*)d_in[1];
    const float* W1     = (const float*)d_in[2];
    const float* U1     = (const float*)d_in[3];
    const float* b1     = (const float*)d_in[4];
    const float* W2     = (const float*)d_in[5];
    const float* U2     = (const float*)d_in[6];
    const float* b2     = (const float*)d_in[7];
    const float* Wo     = (const float*)d_in[8];
    const float* bo     = (const float*)d_in[9];
    float* out = (float*)d_out;

    char* ws = (char*)d_ws;
    const size_t HB = (size_t)M_TOTAL * N_TOTAL * sizeof(ushort);      // 4 MB
    size_t off = 0;
    ushort* h1zero = (ushort*)(ws + off); off += HB;
    ushort* h2x0   = (ushort*)(ws + off); off += HB;
    ushort* h2x1   = (ushort*)(ws + off); off += HB;
    ushort* ring0  = (ushort*)(ws + off); off += HB;
    ushort* ring1  = (ushort*)(ws + off); off += HB;
    ushort* ring2  = (ushort*)(ws + off); off += HB;
    float*  xw2f0  = (float*)(ws + off);  off += (size_t)M_TOTAL * N_TOTAL * 4;
    float*  xw2f1  = (float*)(ws + off);  off += (size_t)M_TOTAL * N_TOTAL * 4;
    ushort* W1T = (ushort*)(ws + off); off += (size_t)N_TOTAL * EMB_D   * 2;
    ushort* U1T = (ushort*)(ws + off); off += (size_t)N_TOTAL * N_TOTAL * 2;
    ushort* W2T = (ushort*)(ws + off); off += (size_t)N_TOTAL * N_TOTAL * 2;
    ushort* U2T = (ushort*)(ws + off); off += (size_t)N_TOTAL * N_TOTAL * 2;
    ushort* embb = (ushort*)(ws + off); off += (size_t)VOCAB * EMB_D * 2;
    ushort* EW1  = (ushort*)(ws + off); off += (size_t)EW_ROWS * N_TOTAL * 2;

    ushort* ring[3] = { ring0, ring1, ring2 };
    float*  xw2f[2] = { xw2f0, xw2f1 };
    ushort* h2x[2]  = { h2x0, h2x1 };

    hipMemsetAsync(h1zero, 0, HB, stream);
    hipMemsetAsync(h2x1,   0, HB, stream);   // h2[-1] zeros (read at i==2)

    emb_convert<<<dim3(12500), 256, 0, stream>>>(embb, emb);
    transpose_convert<<<dim3((EMB_D  / 64) * (N_TOTAL / 64)), 256, 0, stream>>>(W1T, W1, EMB_D,   N_TOTAL);
    transpose_convert<<<dim3((N_TOTAL / 64) * (N_TOTAL / 64)), 256, 0, stream>>>(U1T, U1, N_TOTAL, N_TOTAL);
    transpose_convert<<<dim3((N_TOTAL / 64) * (N_TOTAL / 64)), 256, 0, stream>>>(W2T, W2, N_TOTAL, N_TOTAL);
    transpose_convert<<<dim3((N_TOTAL / 64) * (N_TOTAL / 64)), 256, 0, stream>>>(U2T, U2, N_TOTAL, N_TOTAL);

    ew1_gemm<<<dim3((EW_ROWS / 128) * 8), 256, 0, stream>>>(EW1, embb, W1T);
    gather_xw1<<<dim3(64), 256, 0, stream>>>(ring[0], EW1, tokens, 0);

    for (int i = 0; i <= TSEQ + 1; ++i) {
        const ushort* sl_prev = (i == 0) ? h1zero : ring[(i - 1) % 3];
        ushort* sl_cur  = ring[i % 3];
        ushort* sl_next = ring[(i + 1) % 3];
        float* xw2_dst  = xw2f[(i - 1) & 1];
        const float* xw2_src = xw2f[(i - 2) & 1];
        const ushort* h2prev = h2x[(i - 3) & 1];
        ushort* h2dst = h2x[(i - 2) & 1];
        fused_step<<<dim3(448), 256, 0, stream>>>(
            EW1, tokens, sl_prev, sl_cur, sl_next,
            U1T, b1, W2T, xw2_dst, xw2_src, U2T, b2, h2prev, h2dst, i);
    }

    out_kernel<<<dim3(M_TOTAL / 4), dim3(256), 0, stream>>>(out, h2x[1], Wo, bo);
}

// Round 11
// 3486.497 us; speedup vs baseline: 1.1593x; 1.0877x over previous
//
#include <hip/hip_runtime.h>
#include <math.h>

#define M_TOTAL 2048
#define N_TOTAL 1024
#define TSEQ    80
#define EMB_D   512
#define VOCAB   50000
#define EW_ROWS 50048            // VOCAB padded to 128
#define BK      64

typedef __attribute__((ext_vector_type(8))) short bf16x8;
typedef __attribute__((ext_vector_type(4))) float f32x4;

__device__ __forceinline__ ushort f2bf(float f) {
    union { float f; unsigned u; } v; v.f = f;
    unsigned r = v.u + 0x7FFFu + ((v.u >> 16) & 1u);
    return (ushort)(r >> 16);
}
__device__ __forceinline__ float bf2f(ushort h) {
    union { unsigned u; float f; } v; v.u = ((unsigned)h) << 16;
    return v.f;
}
__device__ __forceinline__ void gload_lds16(const ushort* g, ushort* l) {
    __builtin_amdgcn_global_load_lds(
        (const __attribute__((address_space(1))) void*)g,
        (__attribute__((address_space(3))) void*)l, 16, 0, 0);
}
#define VM0()   asm volatile("s_waitcnt vmcnt(0)" ::: "memory")

// ---------------------------------------------------------------------------
// GEMM core: 128x128 tile, 256 thr (4 waves 2x2, wave-tile 64x64).
// Double-buffered A+B (64 KB LDS -> 2 blocks/CU). T3-minimum schedule:
//   per chunk: stage(c+1) ; compute(c) ; vmcnt(0) ; barrier
// ---------------------------------------------------------------------------
template<int NC>
__device__ __forceinline__ void gemm_core(
    f32x4 (&acc)[4][4],
    const ushort* __restrict__ A, const size_t* __restrict__ ga,
    const ushort* __restrict__ B, const size_t* __restrict__ gb,
    int w, int l,
    ushort (*As)[128 * BK], ushort (*Bs)[128 * BK])
{
    const int wr = w >> 1, wc = w & 1;
    auto stage = [&](int c, int buf) {
        const int k0 = c << 6;
        #pragma unroll
        for (int j = 0; j < 4; ++j)
            gload_lds16(A + ga[j] + k0, &As[buf][(w * 32 + j * 8) * BK + l * 8]);
        #pragma unroll
        for (int j = 0; j < 4; ++j)
            gload_lds16(B + gb[j] + k0, &Bs[buf][(w * 32 + j * 8) * BK + l * 8]);
    };
    stage(0, 0);
    VM0(); __syncthreads();
    #pragma unroll
    for (int c = 0; c < NC; ++c) {
        const int buf = c & 1;
        if (c + 1 < NC) stage(c + 1, buf ^ 1);
        #pragma unroll
        for (int kf = 0; kf < 2; ++kf) {
            const int ke = kf * 32 + (l >> 4) * 8;
            bf16x8 a[4], b[4];
            #pragma unroll
            for (int mf = 0; mf < 4; ++mf) {
                const int row = wr * 64 + mf * 16 + (l & 15);
                a[mf] = *(const bf16x8*)&As[buf][row * BK + (ke ^ ((row & 7) << 3))];
            }
            #pragma unroll
            for (int nf = 0; nf < 4; ++nf) {
                const int row = wc * 64 + nf * 16 + (l & 15);
                b[nf] = *(const bf16x8*)&Bs[buf][row * BK + (ke ^ ((row & 7) << 3))];
            }
            #pragma unroll
            for (int mf = 0; mf < 4; ++mf)
                #pragma unroll
                for (int nf = 0; nf < 4; ++nf)
                    acc[mf][nf] = __builtin_amdgcn_mfma_f32_16x16x32_bf16(
                        a[mf], b[nf], acc[mf][nf], 0, 0, 0);
        }
        VM0(); __syncthreads();
    }
}

// ---------------------------------------------------------------------------
// Fused per-step kernel, grid 448, 2 blocks/CU, single residency round.
// 2x4 HYBRID XCD PINNING: xcd = bid&7 = ((m&3)<<1)|(n&1). Each XCD owns
// m tiles {mi*4 + (xcd>>1)} and n tiles {ni*2 + (xcd&1)}:
//   - A-panels (h-state, the big stream) replicate x2 across XCDs, not x8.
//   - Per-XCD B working set = 3 weights x 512 cols = 3 MB -> L2-resident.
//   bid < 384 : GEMM. g = bid>>3 in 0..47: job = g>>4, r = g&15,
//               m = (r>>2)*4 + (xcd>>1), n = (r&3)*2 + (xcd&1).
//     job0 (J1): h1[i]   = tanh(xw1[i] + h1[i-1]@U1 + b1)   [in-place slab]
//     job1 (J2): xw2[i-1]= h1[i-1]@W2                       [bf16 store]
//     job2 (J3): h2[i-2] = tanh(xw2[i-2] + h2[i-3]@U2 + b2)
//   bid 384..447 : J0 gather xw1[i+1] rows of EW1 -> sl_next (32 rows/block)
// ---------------------------------------------------------------------------
__global__ __launch_bounds__(256, 2) void fused_step(
    const ushort* __restrict__ EW1,
    const int* __restrict__ tok,
    const ushort* __restrict__ sl_prev,   // h1[i-1] (h1zero at i==0)
    ushort* __restrict__ sl_cur,          // xw1[i] -> h1[i] (in place)
    ushort* __restrict__ sl_next,         // J0 dst: xw1[i+1]
    const ushort* __restrict__ U1T, const float* __restrict__ b1,
    const ushort* __restrict__ W2T,
    ushort* __restrict__ xw2_dst,         // bf16
    const ushort* __restrict__ xw2_src,   // bf16
    const ushort* __restrict__ U2T, const float* __restrict__ b2,
    const ushort* __restrict__ h2prev,
    ushort* __restrict__ h2dst,
    int i)
{
    __shared__ ushort As[2][128 * BK];   // 32 KB
    __shared__ ushort Bs[2][128 * BK];   // 32 KB
    const int tid = threadIdx.x;
    const int bid = blockIdx.x;

    if (bid >= 384) {                    // ---- J0: gather xw1[i+1]
        if (i > TSEQ - 2) return;
        const int b = (bid - 384) * 32 + (tid >> 3);
        const int token = tok[b * TSEQ + i + 1];
        const uint4* src = (const uint4*)(EW1 + (size_t)token * N_TOTAL);
        uint4* dst = (uint4*)(sl_next + (size_t)b * N_TOTAL);
        #pragma unroll
        for (int g = 0; g < 16; ++g)
            dst[(tid & 7) + g * 8] = src[(tid & 7) + g * 8];
        return;
    }

    const int w = tid >> 6, l = tid & 63;
    const int xcd = bid & 7, g = bid >> 3;
    const int job = g >> 4;              // 0,1,2
    const int r = g & 15;
    const int m = ((r >> 2) << 2) + (xcd >> 1);   // (r>>2)*4 + xcd/2, 0..15
    const int n = ((r & 3) << 1) + (xcd & 1);     // (r&3)*2 + xcd%2, 0..7
    const int bm0 = m << 7, bn0 = n << 7;

    if (job == 0 && i > TSEQ - 1) return;
    if (job == 1 && (i < 1 || i > TSEQ)) return;
    if (job == 2 && i < 2) return;

    const ushort* A; const ushort* B;
    if (job == 0)      { A = sl_prev; B = U1T; }
    else if (job == 1) { A = sl_prev; B = W2T; }
    else               { A = h2prev;  B = U2T; }

    const int lr = l >> 3;
    const int se = ((l & 7) ^ lr) << 3;
    size_t ga[4], gb[4];
    #pragma unroll
    for (int j = 0; j < 4; ++j) {
        ga[j] = (size_t)(bm0 + w * 32 + j * 8 + lr) * N_TOTAL + se;
        gb[j] = (size_t)(bn0 + w * 32 + j * 8 + lr) * N_TOTAL + se;
    }

    f32x4 acc[4][4] = {};
    gemm_core<16>(acc, A, ga, B, gb, w, l, As, Bs);

    const int wr = w >> 1, wc = w & 1;
    #pragma unroll
    for (int nf = 0; nf < 4; ++nf) {
        const int col = bn0 + wc * 64 + nf * 16 + (l & 15);
        #pragma unroll
        for (int mf = 0; mf < 4; ++mf) {
            const int rb = bm0 + wr * 64 + mf * 16 + (l >> 4) * 4;
            #pragma unroll
            for (int rr = 0; rr < 4; ++rr) {
                const size_t idx = (size_t)(rb + rr) * N_TOTAL + col;
                if (job == 0)
                    sl_cur[idx] = f2bf(tanhf(acc[mf][nf][rr] + bf2f(sl_cur[idx]) + b1[col]));
                else if (job == 1)
                    xw2_dst[idx] = f2bf(acc[mf][nf][rr]);
                else
                    h2dst[idx] = f2bf(tanhf(acc[mf][nf][rr] + bf2f(xw2_src[idx]) + b2[col]));
            }
        }
    }
}

// ---------------------------------------------------------------------------
// EW1[v][n] = embb[v] @ W1^T  (one-time, M=50048 padded, K=512, NC=8)
// ---------------------------------------------------------------------------
__global__ __launch_bounds__(256, 2) void ew1_gemm(
    ushort* __restrict__ EW1,
    const ushort* __restrict__ embb,     // [50000][512]
    const ushort* __restrict__ W1T)      // [1024][512]
{
    __shared__ ushort As[2][128 * BK];
    __shared__ ushort Bs[2][128 * BK];
    const int tid = threadIdx.x;
    const int w = tid >> 6, l = tid & 63;
    const int bid = blockIdx.x;
    const int n = bid & 7, m = bid >> 3;        // m 0..390
    const int bm0 = m << 7, bn0 = n << 7;

    const int lr = l >> 3;
    const int se = ((l & 7) ^ lr) << 3;
    size_t ga[4], gb[4];
    #pragma unroll
    for (int j = 0; j < 4; ++j) {
        int row = bm0 + w * 32 + j * 8 + lr;
        if (row >= VOCAB) row = VOCAB - 1;      // clamp (results discarded)
        ga[j] = (size_t)row * EMB_D + se;
        gb[j] = (size_t)(bn0 + w * 32 + j * 8 + lr) * EMB_D + se;
    }

    f32x4 acc[4][4] = {};
    gemm_core<8>(acc, embb, ga, W1T, gb, w, l, As, Bs);

    const int wr = w >> 1, wc = w & 1;
    #pragma unroll
    for (int nf = 0; nf < 4; ++nf) {
        const int col = bn0 + wc * 64 + nf * 16 + (l & 15);
        #pragma unroll
        for (int mf = 0; mf < 4; ++mf) {
            const int rb = bm0 + wr * 64 + mf * 16 + (l >> 4) * 4;
            #pragma unroll
            for (int r = 0; r < 4; ++r)
                if (rb + r < VOCAB)
                    EW1[(size_t)(rb + r) * N_TOTAL + col] = f2bf(acc[mf][nf][r]);
        }
    }
}

// gather xw1[0] into ring slab (prologue)
__global__ __launch_bounds__(256) void gather_xw1(
    ushort* __restrict__ dst, const ushort* __restrict__ EW1,
    const int* __restrict__ tok, int t)
{
    const int b = blockIdx.x * 32 + (threadIdx.x >> 3);
    const int token = tok[b * TSEQ + t];
    const uint4* src = (const uint4*)(EW1 + (size_t)token * N_TOTAL);
    uint4* d = (uint4*)(dst + (size_t)b * N_TOTAL);
    #pragma unroll
    for (int g = 0; g < 16; ++g)
        d[(threadIdx.x & 7) + g * 8] = src[(threadIdx.x & 7) + g * 8];
}

// emb fp32 -> bf16 (50000*512/8/256 = 12500 blocks)
__global__ __launch_bounds__(256) void emb_convert(
    ushort* __restrict__ dst, const float* __restrict__ src)
{
    const size_t i = ((size_t)blockIdx.x * 256 + threadIdx.x) * 8;
    const float4 v0 = *(const float4*)(src + i);
    const float4 v1 = *(const float4*)(src + i + 4);
    const unsigned w0 = f2bf(v0.x) | (f2bf(v0.y) << 16);
    const unsigned w1 = f2bf(v0.z) | (f2bf(v0.w) << 16);
    const unsigned w2 = f2bf(v1.x) | (f2bf(v1.y) << 16);
    const unsigned w3 = f2bf(v1.z) | (f2bf(v1.w) << 16);
    *(uint4*)(dst + i) = make_uint4(w0, w1, w2, w3);
}

// W [K][N] fp32 -> WT [N][K] bf16
__global__ __launch_bounds__(256) void transpose_convert(
    ushort* __restrict__ outT, const float* __restrict__ in, int K, int N)
{
    __shared__ float tile[64][65];
    const int tiles_n = N >> 6;
    const int k0 = (blockIdx.x / tiles_n) << 6;
    const int n0 = (blockIdx.x % tiles_n) << 6;
    const int tid = threadIdx.x;
    const int r = tid >> 4, c = (tid & 15) << 2;
    #pragma unroll
    for (int i = 0; i < 4; ++i) {
        const float4 v = *(const float4*)(in + (size_t)(k0 + r + i * 16) * N + n0 + c);
        tile[r + i * 16][c + 0] = v.x;
        tile[r + i * 16][c + 1] = v.y;
        tile[r + i * 16][c + 2] = v.z;
        tile[r + i * 16][c + 3] = v.w;
    }
    __syncthreads();
    const int n = tid >> 2, ks = (tid & 3) << 4;
    unsigned pk[8];
    #pragma unroll
    for (int j = 0; j < 8; ++j) {
        const unsigned lo = f2bf(tile[ks + 2 * j][n]);
        const unsigned hi = f2bf(tile[ks + 2 * j + 1][n]);
        pk[j] = lo | (hi << 16);
    }
    ushort* dst = outT + (size_t)(n0 + n) * K + k0 + ks;
    *(uint4*)(dst + 0) = make_uint4(pk[0], pk[1], pk[2], pk[3]);
    *(uint4*)(dst + 8) = make_uint4(pk[4], pk[5], pk[6], pk[7]);
}

__global__ __launch_bounds__(256) void out_kernel(
    float* __restrict__ out, const ushort* __restrict__ h2,
    const float* __restrict__ Wo, const float* __restrict__ bo)
{
    const int row  = blockIdx.x * 4 + (threadIdx.x >> 6);
    const int lane = threadIdx.x & 63;
    const ushort* hr = h2 + (size_t)row * N_TOTAL;
    float s = 0.f;
    for (int k = lane; k < N_TOTAL; k += 64)
        s += bf2f(hr[k]) * Wo[k];
    #pragma unroll
    for (int off = 32; off; off >>= 1)
        s += __shfl_down(s, off);
    if (lane == 0)
        out[row] = 1.f / (1.f + expf(-(s + bo[0])));
}

extern "C" void kernel_launch(void* const* d_in, const int* in_sizes, int n_in,
                              void* d_out, int out_size, void* d_ws, size_t ws_size,
                              hipStream_t stream) {
    const int*   tokens = (const int*)  d_in[0];
    const float* emb    = (const float*)d_in[1];
    const float* W1     = (const float*)d_in[2];
    const float* U1     = (const float*)d_in[3];
    const float* b1     = (const float*)d_in[4];
    const float* W2     = (const float*)d_in[5];
    const float* U2     = (const float*)d_in[6];
    const float* b2     = (const float*)d_in[7];
    const float* Wo     = (const float*)d_in[8];
    const float* bo     = (const float*)d_in[9];
    float* out = (float*)d_out;

    char* ws = (char*)d_ws;
    const size_t HB = (size_t)M_TOTAL * N_TOTAL * sizeof(ushort);      // 4 MB
    size_t off = 0;
    ushort* h1zero = (ushort*)(ws + off); off += HB;
    ushort* h2x0   = (ushort*)(ws + off); off += HB;
    ushort* h2x1   = (ushort*)(ws + off); off += HB;
    ushort* ring0  = (ushort*)(ws + off); off += HB;
    ushort* ring1  = (ushort*)(ws + off); off += HB;
    ushort* ring2  = (ushort*)(ws + off); off += HB;
    ushort* xw2b0  = (ushort*)(ws + off); off += HB;
    ushort* xw2b1  = (ushort*)(ws + off); off += HB;
    ushort* W1T = (ushort*)(ws + off); off += (size_t)N_TOTAL * EMB_D   * 2;
    ushort* U1T = (ushort*)(ws + off); off += (size_t)N_TOTAL * N_TOTAL * 2;
    ushort* W2T = (ushort*)(ws + off); off += (size_t)N_TOTAL * N_TOTAL * 2;
    ushort* U2T = (ushort*)(ws + off); off += (size_t)N_TOTAL * N_TOTAL * 2;
    ushort* embb = (ushort*)(ws + off); off += (size_t)VOCAB * EMB_D * 2;
    ushort* EW1  = (ushort*)(ws + off); off += (size_t)EW_ROWS * N_TOTAL * 2;

    ushort* ring[3] = { ring0, ring1, ring2 };
    ushort* xw2b[2] = { xw2b0, xw2b1 };
    ushort* h2x[2]  = { h2x0, h2x1 };

    hipMemsetAsync(h1zero, 0, HB, stream);
    hipMemsetAsync(h2x1,   0, HB, stream);   // h2[-1] zeros (read at i==2)

    emb_convert<<<dim3(12500), 256, 0, stream>>>(embb, emb);
    transpose_convert<<<dim3((EMB_D  / 64) * (N_TOTAL / 64)), 256, 0, stream>>>(W1T, W1, EMB_D,   N_TOTAL);
    transpose_convert<<<dim3((N_TOTAL / 64) * (N_TOTAL / 64)), 256, 0, stream>>>(U1T, U1, N_TOTAL, N_TOTAL);
    transpose_convert<<<dim3((N_TOTAL / 64) * (N_TOTAL / 64)), 256, 0, stream>>>(W2T, W2, N_TOTAL, N_TOTAL);
    transpose_convert<<<dim3((N_TOTAL / 64) * (N_TOTAL / 64)), 256, 0, stream>>>(U2T, U2, N_TOTAL, N_TOTAL);

    ew1_gemm<<<dim3((EW_ROWS / 128) * 8), 256, 0, stream>>>(EW1, embb, W1T);
    gather_xw1<<<dim3(64), 256, 0, stream>>>(ring[0], EW1, tokens, 0);

    for (int i = 0; i <= TSEQ + 1; ++i) {
        const ushort* sl_prev = (i == 0) ? h1zero : ring[(i - 1) % 3];
        ushort* sl_cur  = ring[i % 3];
        ushort* sl_next = ring[(i + 1) % 3];
        ushort* xw2_dst = xw2b[(i - 1) & 1];
        const ushort* xw2_src = xw2b[(i - 2) & 1];
        const ushort* h2prev = h2x[(i - 3) & 1];
        ushort* h2dst = h2x[(i - 2) & 1];
        fused_step<<<dim3(448), 256, 0, stream>>>(
            EW1, tokens, sl_prev, sl_cur, sl_next,
            U1T, b1, W2T, xw2_dst, xw2_src, U2T, b2, h2prev, h2dst, i);
    }

    out_kernel<<<dim3(M_TOTAL / 4), dim3(256), 0, stream>>>(out, h2x[1], Wo, bo);
}

// Round 12
// 2338.615 us; speedup vs baseline: 1.7283x; 1.4908x over previous
//
#include <hip/hip_runtime.h>
#include <math.h>

#define M_TOTAL 2048
#define N_TOTAL 1024
#define TSEQ    80
#define EMB_D   512
#define VOCAB   50000
#define EW_ROWS 50048            // VOCAB padded to 128
#define BK      64

typedef __attribute__((ext_vector_type(8))) short bf16x8;
typedef __attribute__((ext_vector_type(4))) float f32x4;

__device__ __forceinline__ ushort f2bf(float f) {
    union { float f; unsigned u; } v; v.f = f;
    unsigned r = v.u + 0x7FFFu + ((v.u >> 16) & 1u);
    return (ushort)(r >> 16);
}
__device__ __forceinline__ float bf2f(ushort h) {
    union { unsigned u; float f; } v; v.u = ((unsigned)h) << 16;
    return v.f;
}
__device__ __forceinline__ void gload_lds16(const ushort* g, ushort* l) {
    __builtin_amdgcn_global_load_lds(
        (const __attribute__((address_space(1))) void*)g,
        (__attribute__((address_space(3))) void*)l, 16, 0, 0);
}
#define VMC6()  asm volatile("s_waitcnt vmcnt(6)" ::: "memory")
#define VMC0()  asm volatile("s_waitcnt vmcnt(0)" ::: "memory")
#define VM0()   asm volatile("s_waitcnt vmcnt(0)" ::: "memory")
#define SBAR()  __builtin_amdgcn_s_barrier()
#define SCHED0() __builtin_amdgcn_sched_barrier(0)

// ---------------------------------------------------------------------------
// Fused per-step kernel — R7 structure with balanced layer pairing.
// 128x64 tiles, 256 thr (4 waves 2x2, wave-tile 64x32). Counted-vmcnt
// TRIPLE-buffered pipeline (per chunk: stage(c+1); vmcnt(6); s_barrier;
// setprio(1) MFMA setprio(0)). 72 KB LDS -> 2 blocks/CU.
// Grid 512, layer = bid>>8: with round-robin dispatch CU c holds bids
// {c, c+256} = one L1 (16 chunks) + one L2 (32 chunks) -> uniform 48/CU.
// strip = bid&7 pins each XCD to one 128-col weight strip (L2-resident).
//   L1 (bid<256):  h1[i]  = tanh(xw1[i] + h1[i-1]@U1 + b1)  [in-place slab]
//                  + gathers xw1[i+1] rows of EW1 -> sl_next (8 rows/block)
//   L2 (bid>=256): h2[i-1]= tanh(h1[i-1]@W2 + h2[i-2]@U2 + b2)
// ---------------------------------------------------------------------------
__global__ __launch_bounds__(256) void fused_step(
    const ushort* __restrict__ EW1,
    const int* __restrict__ tok,
    ushort* __restrict__ sl_cur,          // ring[i%3]: xw1[i] -> h1[i]
    const ushort* __restrict__ sl_prev,   // ring[(i-1)%3] = h1[i-1] (or zeros)
    ushort* __restrict__ sl_next,         // ring[(i+1)%3]: gather dst
    const ushort* __restrict__ U1T, const float* __restrict__ b1,
    const ushort* __restrict__ W2T, const ushort* __restrict__ U2T,
    const float* __restrict__ b2,
    const ushort* __restrict__ h2c, ushort* __restrict__ h2n,
    int i)
{
    __shared__ ushort As[3][128 * BK];   // 48 KB
    __shared__ ushort Bs[3][64 * BK];    // 24 KB
    const int tid = threadIdx.x;
    const int w = tid >> 6, l = tid & 63;
    const int wr = w >> 1, wc = w & 1;        // wave grid 2x2, wave-tile 64x32
    const int bid = blockIdx.x;
    const int layer = bid >> 8;               // 0: bids 0..255, 1: 256..511
    const int idx = bid & 255;
    const int strip = idx & 7;                // XCD id == weight strip
    const int r = idx >> 3;                   // 0..31
    const int n = strip * 2 + (r & 1);        // 0..15
    const int m = r >> 1;                     // 0..15
    const int bm0 = m << 7;
    const int bn0 = n << 6;

    if (layer == 0 && i >= TSEQ) return;      // i==80: L2 only
    if (layer == 1 && i < 1) return;          // i==0:  L1 only

    // ---- L1 gather prologue: issue xw1[i+1] row loads BEFORE stage(0) so
    // they drain at the first vmcnt(6) and never perturb the counted waits.
    uint4 gth[4];
    const int dogather = (layer == 0) && (i + 1 < TSEQ);
    ushort* gdst = nullptr;
    if (dogather) {
        const int grow = idx * 8 + (tid >> 5);          // 8 rows per block
        const int token = tok[grow * TSEQ + (i + 1)];
        const uint4* src = (const uint4*)(EW1 + (size_t)token * N_TOTAL);
        gdst = sl_next + (size_t)grow * N_TOTAL;
        #pragma unroll
        for (int j = 0; j < 4; ++j)
            gth[j] = src[(tid & 31) + j * 32];
    }

    // staging thread-constants (XOR-pre-swizzled source granule)
    const int lr = l >> 3;
    const int se = ((l & 7) ^ lr) << 3;
    const size_t ga0 = (size_t)(bm0 + w * 32 + 0  + lr) * N_TOTAL + se;
    const size_t ga1 = (size_t)(bm0 + w * 32 + 8  + lr) * N_TOTAL + se;
    const size_t ga2 = (size_t)(bm0 + w * 32 + 16 + lr) * N_TOTAL + se;
    const size_t ga3 = (size_t)(bm0 + w * 32 + 24 + lr) * N_TOTAL + se;
    const size_t gb0 = (size_t)(bn0 + w * 16 + 0  + lr) * N_TOTAL + se;
    const size_t gb1 = (size_t)(bn0 + w * 16 + 8  + lr) * N_TOTAL + se;
    const int la0 = (w * 32 + 0)  * BK + l * 8;
    const int la1 = (w * 32 + 8)  * BK + l * 8;
    const int la2 = (w * 32 + 16) * BK + l * 8;
    const int la3 = (w * 32 + 24) * BK + l * 8;
    const int lb0 = (w * 16 + 0)  * BK + l * 8;
    const int lb1 = (w * 16 + 8)  * BK + l * 8;

    auto stage = [&](const ushort* __restrict__ A, const ushort* __restrict__ B,
                     int k0, int buf) {
        gload_lds16(A + ga0 + k0, &As[buf][la0]);
        gload_lds16(A + ga1 + k0, &As[buf][la1]);
        gload_lds16(A + ga2 + k0, &As[buf][la2]);
        gload_lds16(A + ga3 + k0, &As[buf][la3]);
        gload_lds16(B + gb0 + k0, &Bs[buf][lb0]);
        gload_lds16(B + gb1 + k0, &Bs[buf][lb1]);
    };

    f32x4 acc[4][2] = {};

    auto compute = [&](int buf) {
        __builtin_amdgcn_s_setprio(1);
        #pragma unroll
        for (int kf = 0; kf < 2; ++kf) {
            const int ke = kf * 32 + (l >> 4) * 8;
            bf16x8 a[4], b[2];
            #pragma unroll
            for (int mf = 0; mf < 4; ++mf) {
                const int row = wr * 64 + mf * 16 + (l & 15);
                a[mf] = *(const bf16x8*)&As[buf][row * BK + (ke ^ ((row & 7) << 3))];
            }
            #pragma unroll
            for (int nf = 0; nf < 2; ++nf) {
                const int row = wc * 32 + nf * 16 + (l & 15);
                b[nf] = *(const bf16x8*)&Bs[buf][row * BK + (ke ^ ((row & 7) << 3))];
            }
            #pragma unroll
            for (int mf = 0; mf < 4; ++mf)
                #pragma unroll
                for (int nf = 0; nf < 2; ++nf)
                    acc[mf][nf] = __builtin_amdgcn_mfma_f32_16x16x32_bf16(
                        a[mf], b[nf], acc[mf][nf], 0, 0, 0);
        }
        __builtin_amdgcn_s_setprio(0);
    };

    if (layer == 0) {
        auto stage_cc = [&](int cc, int buf) { stage(sl_prev, U1T, cc << 6, buf); };
        stage_cc(0, 0);
        int bufc = 0;
        #pragma unroll
        for (int c = 0; c < 16; ++c) {
            int bufn = bufc + 1; if (bufn == 3) bufn = 0;
            if (c + 1 < 16) { stage_cc(c + 1, bufn); VMC6(); }
            else            { VMC0(); }
            SBAR(); SCHED0();
            compute(bufc);
            bufc = bufn;
        }
        #pragma unroll
        for (int nf = 0; nf < 2; ++nf) {
            const int col = bn0 + wc * 32 + nf * 16 + (l & 15);
            const float bz = b1[col];
            #pragma unroll
            for (int mf = 0; mf < 4; ++mf) {
                const int rb = bm0 + wr * 64 + mf * 16 + (l >> 4) * 4;
                #pragma unroll
                for (int rr = 0; rr < 4; ++rr) {
                    const size_t id2 = (size_t)(rb + rr) * N_TOTAL + col;
                    sl_cur[id2] = f2bf(tanhf(acc[mf][nf][rr] + bf2f(sl_cur[id2]) + bz));
                }
            }
        }
        if (dogather) {
            uint4* d = (uint4*)gdst;
            #pragma unroll
            for (int j = 0; j < 4; ++j)
                d[(tid & 31) + j * 32] = gth[j];
        }
    } else {
        auto stage_cc = [&](int cc, int buf) {
            if (cc < 16) stage(sl_prev, W2T, cc << 6, buf);
            else         stage(h2c,     U2T, (cc - 16) << 6, buf);
        };
        stage_cc(0, 0);
        int bufc = 0;
        #pragma unroll
        for (int c = 0; c < 32; ++c) {
            int bufn = bufc + 1; if (bufn == 3) bufn = 0;
            if (c + 1 < 32) { stage_cc(c + 1, bufn); VMC6(); }
            else            { VMC0(); }
            SBAR(); SCHED0();
            compute(bufc);
            bufc = bufn;
        }
        #pragma unroll
        for (int nf = 0; nf < 2; ++nf) {
            const int col = bn0 + wc * 32 + nf * 16 + (l & 15);
            const float bz = b2[col];
            #pragma unroll
            for (int mf = 0; mf < 4; ++mf) {
                const int rb = bm0 + wr * 64 + mf * 16 + (l >> 4) * 4;
                #pragma unroll
                for (int rr = 0; rr < 4; ++rr)
                    h2n[(size_t)(rb + rr) * N_TOTAL + col] =
                        f2bf(tanhf(acc[mf][nf][rr] + bz));
            }
        }
    }
}

// ---------------------------------------------------------------------------
// EW1[v][n] = embb[v] @ W1^T (one-time, M=50048 padded, K=512). 128x128 tile,
// 256 thr, 2-phase double-buffer (HBM-bound; measured ~102 us).
// ---------------------------------------------------------------------------
__global__ __launch_bounds__(256, 2) void ew1_gemm(
    ushort* __restrict__ EW1,
    const ushort* __restrict__ embb,     // [50000][512]
    const ushort* __restrict__ W1T)      // [1024][512]
{
    __shared__ ushort As[2][128 * BK];
    __shared__ ushort Bs[2][128 * BK];
    const int tid = threadIdx.x;
    const int w = tid >> 6, l = tid & 63;
    const int wr = w >> 1, wc = w & 1;
    const int bid = blockIdx.x;
    const int n = bid & 7, m = bid >> 3;        // m 0..390
    const int bm0 = m << 7, bn0 = n << 7;

    const int lr = l >> 3;
    const int se = ((l & 7) ^ lr) << 3;
    size_t ga[4], gb[4];
    #pragma unroll
    for (int j = 0; j < 4; ++j) {
        int row = bm0 + w * 32 + j * 8 + lr;
        if (row >= VOCAB) row = VOCAB - 1;      // clamp (results discarded)
        ga[j] = (size_t)row * EMB_D + se;
        gb[j] = (size_t)(bn0 + w * 32 + j * 8 + lr) * EMB_D + se;
    }

    auto stage = [&](int c, int buf) {
        const int k0 = c << 6;
        #pragma unroll
        for (int j = 0; j < 4; ++j)
            gload_lds16(embb + ga[j] + k0, &As[buf][(w * 32 + j * 8) * BK + l * 8]);
        #pragma unroll
        for (int j = 0; j < 4; ++j)
            gload_lds16(W1T + gb[j] + k0, &Bs[buf][(w * 32 + j * 8) * BK + l * 8]);
    };

    f32x4 acc[4][4] = {};
    stage(0, 0);
    VM0(); __syncthreads();
    #pragma unroll
    for (int c = 0; c < 8; ++c) {
        const int buf = c & 1;
        if (c + 1 < 8) stage(c + 1, buf ^ 1);
        #pragma unroll
        for (int kf = 0; kf < 2; ++kf) {
            const int ke = kf * 32 + (l >> 4) * 8;
            bf16x8 a[4], b[4];
            #pragma unroll
            for (int mf = 0; mf < 4; ++mf) {
                const int row = wr * 64 + mf * 16 + (l & 15);
                a[mf] = *(const bf16x8*)&As[buf][row * BK + (ke ^ ((row & 7) << 3))];
            }
            #pragma unroll
            for (int nf = 0; nf < 4; ++nf) {
                const int row = wc * 64 + nf * 16 + (l & 15);
                b[nf] = *(const bf16x8*)&Bs[buf][row * BK + (ke ^ ((row & 7) << 3))];
            }
            #pragma unroll
            for (int mf = 0; mf < 4; ++mf)
                #pragma unroll
                for (int nf = 0; nf < 4; ++nf)
                    acc[mf][nf] = __builtin_amdgcn_mfma_f32_16x16x32_bf16(
                        a[mf], b[nf], acc[mf][nf], 0, 0, 0);
        }
        VM0(); __syncthreads();
    }

    #pragma unroll
    for (int nf = 0; nf < 4; ++nf) {
        const int col = bn0 + wc * 64 + nf * 16 + (l & 15);
        #pragma unroll
        for (int mf = 0; mf < 4; ++mf) {
            const int rb = bm0 + wr * 64 + mf * 16 + (l >> 4) * 4;
            #pragma unroll
            for (int rr = 0; rr < 4; ++rr)
                if (rb + rr < VOCAB)
                    EW1[(size_t)(rb + rr) * N_TOTAL + col] = f2bf(acc[mf][nf][rr]);
        }
    }
}

// gather xw1[0] into ring slab (prologue)
__global__ __launch_bounds__(256) void gather_xw1(
    ushort* __restrict__ dst, const ushort* __restrict__ EW1,
    const int* __restrict__ tok, int t)
{
    const int b = blockIdx.x * 32 + (threadIdx.x >> 3);
    const int token = tok[b * TSEQ + t];
    const uint4* src = (const uint4*)(EW1 + (size_t)token * N_TOTAL);
    uint4* d = (uint4*)(dst + (size_t)b * N_TOTAL);
    #pragma unroll
    for (int g = 0; g < 16; ++g)
        d[(threadIdx.x & 7) + g * 8] = src[(threadIdx.x & 7) + g * 8];
}

// emb fp32 -> bf16 (50000*512/8/256 = 12500 blocks)
__global__ __launch_bounds__(256) void emb_convert(
    ushort* __restrict__ dst, const float* __restrict__ src)
{
    const size_t i = ((size_t)blockIdx.x * 256 + threadIdx.x) * 8;
    const float4 v0 = *(const float4*)(src + i);
    const float4 v1 = *(const float4*)(src + i + 4);
    const unsigned w0 = f2bf(v0.x) | (f2bf(v0.y) << 16);
    const unsigned w1 = f2bf(v0.z) | (f2bf(v0.w) << 16);
    const unsigned w2 = f2bf(v1.x) | (f2bf(v1.y) << 16);
    const unsigned w3 = f2bf(v1.z) | (f2bf(v1.w) << 16);
    *(uint4*)(dst + i) = make_uint4(w0, w1, w2, w3);
}

// W [K][N] fp32 -> WT [N][K] bf16
__global__ __launch_bounds__(256) void transpose_convert(
    ushort* __restrict__ outT, const float* __restrict__ in, int K, int N)
{
    __shared__ float tile[64][65];
    const int tiles_n = N >> 6;
    const int k0 = (blockIdx.x / tiles_n) << 6;
    const int n0 = (blockIdx.x % tiles_n) << 6;
    const int tid = threadIdx.x;
    const int r = tid >> 4, c = (tid & 15) << 2;
    #pragma unroll
    for (int i = 0; i < 4; ++i) {
        const float4 v = *(const float4*)(in + (size_t)(k0 + r + i * 16) * N + n0 + c);
        tile[r + i * 16][c + 0] = v.x;
        tile[r + i * 16][c + 1] = v.y;
        tile[r + i * 16][c + 2] = v.z;
        tile[r + i * 16][c + 3] = v.w;
    }
    __syncthreads();
    const int n = tid >> 2, ks = (tid & 3) << 4;
    unsigned pk[8];
    #pragma unroll
    for (int j = 0; j < 8; ++j) {
        const unsigned lo = f2bf(tile[ks + 2 * j][n]);
        const unsigned hi = f2bf(tile[ks + 2 * j + 1][n]);
        pk[j] = lo | (hi << 16);
    }
    ushort* dst = outT + (size_t)(n0 + n) * K + k0 + ks;
    *(uint4*)(dst + 0) = make_uint4(pk[0], pk[1], pk[2], pk[3]);
    *(uint4*)(dst + 8) = make_uint4(pk[4], pk[5], pk[6], pk[7]);
}

__global__ __launch_bounds__(256) void out_kernel(
    float* __restrict__ out, const ushort* __restrict__ h2,
    const float* __restrict__ Wo, const float* __restrict__ bo)
{
    const int row  = blockIdx.x * 4 + (threadIdx.x >> 6);
    const int lane = threadIdx.x & 63;
    const ushort* hr = h2 + (size_t)row * N_TOTAL;
    float s = 0.f;
    for (int k = lane; k < N_TOTAL; k += 64)
        s += bf2f(hr[k]) * Wo[k];
    #pragma unroll
    for (int off = 32; off; off >>= 1)
        s += __shfl_down(s, off);
    if (lane == 0)
        out[row] = 1.f / (1.f + expf(-(s + bo[0])));
}

extern "C" void kernel_launch(void* const* d_in, const int* in_sizes, int n_in,
                              void* d_out, int out_size, void* d_ws, size_t ws_size,
                              hipStream_t stream) {
    const int*   tokens = (const int*)  d_in[0];
    const float* emb    = (const float*)d_in[1];
    const float* W1     = (const float*)d_in[2];
    const float* U1     = (const float*)d_in[3];
    const float* b1     = (const float*)d_in[4];
    const float* W2     = (const float*)d_in[5];
    const float* U2     = (const float*)d_in[6];
    const float* b2     = (const float*)d_in[7];
    const float* Wo     = (const float*)d_in[8];
    const float* bo     = (const float*)d_in[9];
    float* out = (float*)d_out;

    char* ws = (char*)d_ws;
    const size_t HB = (size_t)M_TOTAL * N_TOTAL * sizeof(ushort);      // 4 MB
    size_t off = 0;
    ushort* h1zero = (ushort*)(ws + off); off += HB;
    ushort* h2a    = (ushort*)(ws + off); off += HB;
    ushort* h2b    = (ushort*)(ws + off); off += HB;
    ushort* ring0  = (ushort*)(ws + off); off += HB;
    ushort* ring1  = (ushort*)(ws + off); off += HB;
    ushort* ring2  = (ushort*)(ws + off); off += HB;
    ushort* W1T = (ushort*)(ws + off); off += (size_t)N_TOTAL * EMB_D   * 2;
    ushort* U1T = (ushort*)(ws + off); off += (size_t)N_TOTAL * N_TOTAL * 2;
    ushort* W2T = (ushort*)(ws + off); off += (size_t)N_TOTAL * N_TOTAL * 2;
    ushort* U2T = (ushort*)(ws + off); off += (size_t)N_TOTAL * N_TOTAL * 2;
    ushort* embb = (ushort*)(ws + off); off += (size_t)VOCAB * EMB_D * 2;
    ushort* EW1  = (ushort*)(ws + off); off += (size_t)EW_ROWS * N_TOTAL * 2;

    ushort* ring[3] = { ring0, ring1, ring2 };

    hipMemsetAsync(h1zero, 0, HB, stream);

    emb_convert<<<dim3(12500), 256, 0, stream>>>(embb, emb);
    transpose_convert<<<dim3((EMB_D  / 64) * (N_TOTAL / 64)), 256, 0, stream>>>(W1T, W1, EMB_D,   N_TOTAL);
    transpose_convert<<<dim3((N_TOTAL / 64) * (N_TOTAL / 64)), 256, 0, stream>>>(U1T, U1, N_TOTAL, N_TOTAL);
    transpose_convert<<<dim3((N_TOTAL / 64) * (N_TOTAL / 64)), 256, 0, stream>>>(W2T, W2, N_TOTAL, N_TOTAL);
    transpose_convert<<<dim3((N_TOTAL / 64) * (N_TOTAL / 64)), 256, 0, stream>>>(U2T, U2, N_TOTAL, N_TOTAL);

    ew1_gemm<<<dim3((EW_ROWS / 128) * 8), 256, 0, stream>>>(EW1, embb, W1T);
    gather_xw1<<<dim3(64), 256, 0, stream>>>(ring[0], EW1, tokens, 0);

    ushort* h2c = h2a; ushort* h2n = h2b;
    for (int i = 0; i <= TSEQ; ++i) {
        ushort* sl_cur = ring[i % 3];
        const ushort* sl_prev = (i == 0) ? h1zero : ring[(i - 1) % 3];
        ushort* sl_next = ring[(i + 1) % 3];
        fused_step<<<dim3(512), 256, 0, stream>>>(
            EW1, tokens, sl_cur, sl_prev, sl_next,
            U1T, b1, W2T, U2T, b2, h2c, h2n, i);
        if (i >= 1) { ushort* t = h2c; h2c = h2n; h2n = t; }
    }

    out_kernel<<<dim3(M_TOTAL / 4), dim3(256), 0, stream>>>(out, h2c, Wo, bo);
}

// Round 13
// 2245.554 us; speedup vs baseline: 1.8000x; 1.0414x over previous
//
#include <hip/hip_runtime.h>
#include <math.h>

#define M_TOTAL 2048
#define N_TOTAL 1024
#define TSEQ    80
#define EMB_D   512
#define VOCAB   50000
#define EW_ROWS 50048            // VOCAB padded to 128
#define BK      64

typedef __attribute__((ext_vector_type(8))) short bf16x8;
typedef __attribute__((ext_vector_type(4))) float f32x4;

__device__ __forceinline__ ushort f2bf(float f) {
    union { float f; unsigned u; } v; v.f = f;
    unsigned r = v.u + 0x7FFFu + ((v.u >> 16) & 1u);
    return (ushort)(r >> 16);
}
__device__ __forceinline__ float bf2f(ushort h) {
    union { unsigned u; float f; } v; v.u = ((unsigned)h) << 16;
    return v.f;
}
__device__ __forceinline__ void gload_lds16(const ushort* g, ushort* l) {
    __builtin_amdgcn_global_load_lds(
        (const __attribute__((address_space(1))) void*)g,
        (__attribute__((address_space(3))) void*)l, 16, 0, 0);
}
#define VMC6()  asm volatile("s_waitcnt vmcnt(6)" ::: "memory")
#define VMC0()  asm volatile("s_waitcnt vmcnt(0)" ::: "memory")
#define VM0()   asm volatile("s_waitcnt vmcnt(0)" ::: "memory")
#define SBAR()  __builtin_amdgcn_s_barrier()
#define SCHED0() __builtin_amdgcn_sched_barrier(0)

// ---------------------------------------------------------------------------
// Fused per-step kernel — R12 structure; ONLY the tile<->XCD mapping changed.
// (4x2) HYBRID XCD PINNING: xcd = bid&7 = (mg<<1)|ng, mg=0..3, ng=0..1.
//   m = mg*4 + (idx&3)   (idx = (bid>>3)&31)   -> A-panels replicate x2
//   n = ng*8 + (idx>>2)                        -> B halves replicate x4
// Per-step L2-fill = A(8MB)x2 + B(6MB)x4 + xw(4MB) ~= 44 MB vs 74 MB before.
// Per-XCD L2 working set: A 1MB (m-group) + B 3MB (col-half of U1,W2,U2).
// Counted-vmcnt triple-buffered pipeline, 72 KB LDS -> 2 blocks/CU.
// layer = bid>>8: CU c holds bids {c, c+256} = one L1(16ch) + one L2(32ch).
//   L1 (bid<256):  h1[i]  = tanh(xw1[i] + h1[i-1]@U1 + b1)  [in-place slab]
//                  + gathers xw1[i+1] rows of EW1 -> sl_next (8 rows/block)
//   L2 (bid>=256): h2[i-1]= tanh(h1[i-1]@W2 + h2[i-2]@U2 + b2)
// ---------------------------------------------------------------------------
__global__ __launch_bounds__(256) void fused_step(
    const ushort* __restrict__ EW1,
    const int* __restrict__ tok,
    ushort* __restrict__ sl_cur,          // ring[i%3]: xw1[i] -> h1[i]
    const ushort* __restrict__ sl_prev,   // ring[(i-1)%3] = h1[i-1] (or zeros)
    ushort* __restrict__ sl_next,         // ring[(i+1)%3]: gather dst
    const ushort* __restrict__ U1T, const float* __restrict__ b1,
    const ushort* __restrict__ W2T, const ushort* __restrict__ U2T,
    const float* __restrict__ b2,
    const ushort* __restrict__ h2c, ushort* __restrict__ h2n,
    int i)
{
    __shared__ ushort As[3][128 * BK];   // 48 KB
    __shared__ ushort Bs[3][64 * BK];    // 24 KB
    const int tid = threadIdx.x;
    const int w = tid >> 6, l = tid & 63;
    const int wr = w >> 1, wc = w & 1;        // wave grid 2x2, wave-tile 64x32
    const int bid = blockIdx.x;
    const int layer = bid >> 8;               // 0: bids 0..255, 1: 256..511
    const int gidx = bid & 255;               // gather row-block id (L1)
    const int xcd = bid & 7;                  // XCD under round-robin dispatch
    const int mg = xcd >> 1;                  // m-group 0..3 (A pinning x2)
    const int ng = xcd & 1;                   // n-group 0..1 (B pinning x4)
    const int idx = (bid >> 3) & 31;          // 0..31
    const int m = mg * 4 + (idx & 3);         // 0..15
    const int n = ng * 8 + (idx >> 2);        // 0..15
    const int bm0 = m << 7;
    const int bn0 = n << 6;

    if (layer == 0 && i >= TSEQ) return;      // i==80: L2 only
    if (layer == 1 && i < 1) return;          // i==0:  L1 only

    // ---- L1 gather prologue: issue xw1[i+1] row loads BEFORE stage(0) so
    // they drain at the first vmcnt(6) and never perturb the counted waits.
    uint4 gth[4];
    const int dogather = (layer == 0) && (i + 1 < TSEQ);
    ushort* gdst = nullptr;
    if (dogather) {
        const int grow = gidx * 8 + (tid >> 5);          // 8 rows per block
        const int token = tok[grow * TSEQ + (i + 1)];
        const uint4* src = (const uint4*)(EW1 + (size_t)token * N_TOTAL);
        gdst = sl_next + (size_t)grow * N_TOTAL;
        #pragma unroll
        for (int j = 0; j < 4; ++j)
            gth[j] = src[(tid & 31) + j * 32];
    }

    // staging thread-constants (XOR-pre-swizzled source granule)
    const int lr = l >> 3;
    const int se = ((l & 7) ^ lr) << 3;
    const size_t ga0 = (size_t)(bm0 + w * 32 + 0  + lr) * N_TOTAL + se;
    const size_t ga1 = (size_t)(bm0 + w * 32 + 8  + lr) * N_TOTAL + se;
    const size_t ga2 = (size_t)(bm0 + w * 32 + 16 + lr) * N_TOTAL + se;
    const size_t ga3 = (size_t)(bm0 + w * 32 + 24 + lr) * N_TOTAL + se;
    const size_t gb0 = (size_t)(bn0 + w * 16 + 0  + lr) * N_TOTAL + se;
    const size_t gb1 = (size_t)(bn0 + w * 16 + 8  + lr) * N_TOTAL + se;
    const int la0 = (w * 32 + 0)  * BK + l * 8;
    const int la1 = (w * 32 + 8)  * BK + l * 8;
    const int la2 = (w * 32 + 16) * BK + l * 8;
    const int la3 = (w * 32 + 24) * BK + l * 8;
    const int lb0 = (w * 16 + 0)  * BK + l * 8;
    const int lb1 = (w * 16 + 8)  * BK + l * 8;

    auto stage = [&](const ushort* __restrict__ A, const ushort* __restrict__ B,
                     int k0, int buf) {
        gload_lds16(A + ga0 + k0, &As[buf][la0]);
        gload_lds16(A + ga1 + k0, &As[buf][la1]);
        gload_lds16(A + ga2 + k0, &As[buf][la2]);
        gload_lds16(A + ga3 + k0, &As[buf][la3]);
        gload_lds16(B + gb0 + k0, &Bs[buf][lb0]);
        gload_lds16(B + gb1 + k0, &Bs[buf][lb1]);
    };

    f32x4 acc[4][2] = {};

    auto compute = [&](int buf) {
        __builtin_amdgcn_s_setprio(1);
        #pragma unroll
        for (int kf = 0; kf < 2; ++kf) {
            const int ke = kf * 32 + (l >> 4) * 8;
            bf16x8 a[4], b[2];
            #pragma unroll
            for (int mf = 0; mf < 4; ++mf) {
                const int row = wr * 64 + mf * 16 + (l & 15);
                a[mf] = *(const bf16x8*)&As[buf][row * BK + (ke ^ ((row & 7) << 3))];
            }
            #pragma unroll
            for (int nf = 0; nf < 2; ++nf) {
                const int row = wc * 32 + nf * 16 + (l & 15);
                b[nf] = *(const bf16x8*)&Bs[buf][row * BK + (ke ^ ((row & 7) << 3))];
            }
            #pragma unroll
            for (int mf = 0; mf < 4; ++mf)
                #pragma unroll
                for (int nf = 0; nf < 2; ++nf)
                    acc[mf][nf] = __builtin_amdgcn_mfma_f32_16x16x32_bf16(
                        a[mf], b[nf], acc[mf][nf], 0, 0, 0);
        }
        __builtin_amdgcn_s_setprio(0);
    };

    if (layer == 0) {
        auto stage_cc = [&](int cc, int buf) { stage(sl_prev, U1T, cc << 6, buf); };
        stage_cc(0, 0);
        int bufc = 0;
        #pragma unroll
        for (int c = 0; c < 16; ++c) {
            int bufn = bufc + 1; if (bufn == 3) bufn = 0;
            if (c + 1 < 16) { stage_cc(c + 1, bufn); VMC6(); }
            else            { VMC0(); }
            SBAR(); SCHED0();
            compute(bufc);
            bufc = bufn;
        }
        #pragma unroll
        for (int nf = 0; nf < 2; ++nf) {
            const int col = bn0 + wc * 32 + nf * 16 + (l & 15);
            const float bz = b1[col];
            #pragma unroll
            for (int mf = 0; mf < 4; ++mf) {
                const int rb = bm0 + wr * 64 + mf * 16 + (l >> 4) * 4;
                #pragma unroll
                for (int rr = 0; rr < 4; ++rr) {
                    const size_t id2 = (size_t)(rb + rr) * N_TOTAL + col;
                    sl_cur[id2] = f2bf(tanhf(acc[mf][nf][rr] + bf2f(sl_cur[id2]) + bz));
                }
            }
        }
        if (dogather) {
            uint4* d = (uint4*)gdst;
            #pragma unroll
            for (int j = 0; j < 4; ++j)
                d[(tid & 31) + j * 32] = gth[j];
        }
    } else {
        auto stage_cc = [&](int cc, int buf) {
            if (cc < 16) stage(sl_prev, W2T, cc << 6, buf);
            else         stage(h2c,     U2T, (cc - 16) << 6, buf);
        };
        stage_cc(0, 0);
        int bufc = 0;
        #pragma unroll
        for (int c = 0; c < 32; ++c) {
            int bufn = bufc + 1; if (bufn == 3) bufn = 0;
            if (c + 1 < 32) { stage_cc(c + 1, bufn); VMC6(); }
            else            { VMC0(); }
            SBAR(); SCHED0();
            compute(bufc);
            bufc = bufn;
        }
        #pragma unroll
        for (int nf = 0; nf < 2; ++nf) {
            const int col = bn0 + wc * 32 + nf * 16 + (l & 15);
            const float bz = b2[col];
            #pragma unroll
            for (int mf = 0; mf < 4; ++mf) {
                const int rb = bm0 + wr * 64 + mf * 16 + (l >> 4) * 4;
                #pragma unroll
                for (int rr = 0; rr < 4; ++rr)
                    h2n[(size_t)(rb + rr) * N_TOTAL + col] =
                        f2bf(tanhf(acc[mf][nf][rr] + bz));
            }
        }
    }
}

// ---------------------------------------------------------------------------
// EW1[v][n] = embb[v] @ W1^T (one-time, M=50048 padded, K=512). 128x128 tile,
// 256 thr, 2-phase double-buffer (fill-BW-bound; measured ~101 us).
// ---------------------------------------------------------------------------
__global__ __launch_bounds__(256, 2) void ew1_gemm(
    ushort* __restrict__ EW1,
    const ushort* __restrict__ embb,     // [50000][512]
    const ushort* __restrict__ W1T)      // [1024][512]
{
    __shared__ ushort As[2][128 * BK];
    __shared__ ushort Bs[2][128 * BK];
    const int tid = threadIdx.x;
    const int w = tid >> 6, l = tid & 63;
    const int wr = w >> 1, wc = w & 1;
    const int bid = blockIdx.x;
    const int n = bid & 7, m = bid >> 3;        // m 0..390
    const int bm0 = m << 7, bn0 = n << 7;

    const int lr = l >> 3;
    const int se = ((l & 7) ^ lr) << 3;
    size_t ga[4], gb[4];
    #pragma unroll
    for (int j = 0; j < 4; ++j) {
        int row = bm0 + w * 32 + j * 8 + lr;
        if (row >= VOCAB) row = VOCAB - 1;      // clamp (results discarded)
        ga[j] = (size_t)row * EMB_D + se;
        gb[j] = (size_t)(bn0 + w * 32 + j * 8 + lr) * EMB_D + se;
    }

    auto stage = [&](int c, int buf) {
        const int k0 = c << 6;
        #pragma unroll
        for (int j = 0; j < 4; ++j)
            gload_lds16(embb + ga[j] + k0, &As[buf][(w * 32 + j * 8) * BK + l * 8]);
        #pragma unroll
        for (int j = 0; j < 4; ++j)
            gload_lds16(W1T + gb[j] + k0, &Bs[buf][(w * 32 + j * 8) * BK + l * 8]);
    };

    f32x4 acc[4][4] = {};
    stage(0, 0);
    VM0(); __syncthreads();
    #pragma unroll
    for (int c = 0; c < 8; ++c) {
        const int buf = c & 1;
        if (c + 1 < 8) stage(c + 1, buf ^ 1);
        #pragma unroll
        for (int kf = 0; kf < 2; ++kf) {
            const int ke = kf * 32 + (l >> 4) * 8;
            bf16x8 a[4], b[4];
            #pragma unroll
            for (int mf = 0; mf < 4; ++mf) {
                const int row = wr * 64 + mf * 16 + (l & 15);
                a[mf] = *(const bf16x8*)&As[buf][row * BK + (ke ^ ((row & 7) << 3))];
            }
            #pragma unroll
            for (int nf = 0; nf < 4; ++nf) {
                const int row = wc * 64 + nf * 16 + (l & 15);
                b[nf] = *(const bf16x8*)&Bs[buf][row * BK + (ke ^ ((row & 7) << 3))];
            }
            #pragma unroll
            for (int mf = 0; mf < 4; ++mf)
                #pragma unroll
                for (int nf = 0; nf < 4; ++nf)
                    acc[mf][nf] = __builtin_amdgcn_mfma_f32_16x16x32_bf16(
                        a[mf], b[nf], acc[mf][nf], 0, 0, 0);
        }
        VM0(); __syncthreads();
    }

    #pragma unroll
    for (int nf = 0; nf < 4; ++nf) {
        const int col = bn0 + wc * 64 + nf * 16 + (l & 15);
        #pragma unroll
        for (int mf = 0; mf < 4; ++mf) {
            const int rb = bm0 + wr * 64 + mf * 16 + (l >> 4) * 4;
            #pragma unroll
            for (int rr = 0; rr < 4; ++rr)
                if (rb + rr < VOCAB)
                    EW1[(size_t)(rb + rr) * N_TOTAL + col] = f2bf(acc[mf][nf][rr]);
        }
    }
}

// gather xw1[0] into ring slab (prologue)
__global__ __launch_bounds__(256) void gather_xw1(
    ushort* __restrict__ dst, const ushort* __restrict__ EW1,
    const int* __restrict__ tok, int t)
{
    const int b = blockIdx.x * 32 + (threadIdx.x >> 3);
    const int token = tok[b * TSEQ + t];
    const uint4* src = (const uint4*)(EW1 + (size_t)token * N_TOTAL);
    uint4* d = (uint4*)(dst + (size_t)b * N_TOTAL);
    #pragma unroll
    for (int g = 0; g < 16; ++g)
        d[(threadIdx.x & 7) + g * 8] = src[(threadIdx.x & 7) + g * 8];
}

// emb fp32 -> bf16 (50000*512/8/256 = 12500 blocks)
__global__ __launch_bounds__(256) void emb_convert(
    ushort* __restrict__ dst, const float* __restrict__ src)
{
    const size_t i = ((size_t)blockIdx.x * 256 + threadIdx.x) * 8;
    const float4 v0 = *(const float4*)(src + i);
    const float4 v1 = *(const float4*)(src + i + 4);
    const unsigned w0 = f2bf(v0.x) | (f2bf(v0.y) << 16);
    const unsigned w1 = f2bf(v0.z) | (f2bf(v0.w) << 16);
    const unsigned w2 = f2bf(v1.x) | (f2bf(v1.y) << 16);
    const unsigned w3 = f2bf(v1.z) | (f2bf(v1.w) << 16);
    *(uint4*)(dst + i) = make_uint4(w0, w1, w2, w3);
}

// W [K][N] fp32 -> WT [N][K] bf16
__global__ __launch_bounds__(256) void transpose_convert(
    ushort* __restrict__ outT, const float* __restrict__ in, int K, int N)
{
    __shared__ float tile[64][65];
    const int tiles_n = N >> 6;
    const int k0 = (blockIdx.x / tiles_n) << 6;
    const int n0 = (blockIdx.x % tiles_n) << 6;
    const int tid = threadIdx.x;
    const int r = tid >> 4, c = (tid & 15) << 2;
    #pragma unroll
    for (int i = 0; i < 4; ++i) {
        const float4 v = *(const float4*)(in + (size_t)(k0 + r + i * 16) * N + n0 + c);
        tile[r + i * 16][c + 0] = v.x;
        tile[r + i * 16][c + 1] = v.y;
        tile[r + i * 16][c + 2] = v.z;
        tile[r + i * 16][c + 3] = v.w;
    }
    __syncthreads();
    const int n = tid >> 2, ks = (tid & 3) << 4;
    unsigned pk[8];
    #pragma unroll
    for (int j = 0; j < 8; ++j) {
        const unsigned lo = f2bf(tile[ks + 2 * j][n]);
        const unsigned hi = f2bf(tile[ks + 2 * j + 1][n]);
        pk[j] = lo | (hi << 16);
    }
    ushort* dst = outT + (size_t)(n0 + n) * K + k0 + ks;
    *(uint4*)(dst + 0) = make_uint4(pk[0], pk[1], pk[2], pk[3]);
    *(uint4*)(dst + 8) = make_uint4(pk[4], pk[5], pk[6], pk[7]);
}

__global__ __launch_bounds__(256) void out_kernel(
    float* __restrict__ out, const ushort* __restrict__ h2,
    const float* __restrict__ Wo, const float* __restrict__ bo)
{
    const int row  = blockIdx.x * 4 + (threadIdx.x >> 6);
    const int lane = threadIdx.x & 63;
    const ushort* hr = h2 + (size_t)row * N_TOTAL;
    float s = 0.f;
    for (int k = lane; k < N_TOTAL; k += 64)
        s += bf2f(hr[k]) * Wo[k];
    #pragma unroll
    for (int off = 32; off; off >>= 1)
        s += __shfl_down(s, off);
    if (lane == 0)
        out[row] = 1.f / (1.f + expf(-(s + bo[0])));
}

extern "C" void kernel_launch(void* const* d_in, const int* in_sizes, int n_in,
                              void* d_out, int out_size, void* d_ws, size_t ws_size,
                              hipStream_t stream) {
    const int*   tokens = (const int*)  d_in[0];
    const float* emb    = (const float*)d_in[1];
    const float* W1     = (const float*)d_in[2];
    const float* U1     = (const float*)d_in[3];
    const float* b1     = (const float*)d_in[4];
    const float* W2     = (const float*)d_in[5];
    const float* U2     = (const float*)d_in[6];
    const float* b2     = (const float*)d_in[7];
    const float* Wo     = (const float*)d_in[8];
    const float* bo     = (const float*)d_in[9];
    float* out = (float*)d_out;

    char* ws = (char*)d_ws;
    const size_t HB = (size_t)M_TOTAL * N_TOTAL * sizeof(ushort);      // 4 MB
    size_t off = 0;
    ushort* h1zero = (ushort*)(ws + off); off += HB;
    ushort* h2a    = (ushort*)(ws + off); off += HB;
    ushort* h2b    = (ushort*)(ws + off); off += HB;
    ushort* ring0  = (ushort*)(ws + off); off += HB;
    ushort* ring1  = (ushort*)(ws + off); off += HB;
    ushort* ring2  = (ushort*)(ws + off); off += HB;
    ushort* W1T = (ushort*)(ws + off); off += (size_t)N_TOTAL * EMB_D   * 2;
    ushort* U1T = (ushort*)(ws + off); off += (size_t)N_TOTAL * N_TOTAL * 2;
    ushort* W2T = (ushort*)(ws + off); off += (size_t)N_TOTAL * N_TOTAL * 2;
    ushort* U2T = (ushort*)(ws + off); off += (size_t)N_TOTAL * N_TOTAL * 2;
    ushort* embb = (ushort*)(ws + off); off += (size_t)VOCAB * EMB_D * 2;
    ushort* EW1  = (ushort*)(ws + off); off += (size_t)EW_ROWS * N_TOTAL * 2;

    ushort* ring[3] = { ring0, ring1, ring2 };

    hipMemsetAsync(h1zero, 0, HB, stream);

    emb_convert<<<dim3(12500), 256, 0, stream>>>(embb, emb);
    transpose_convert<<<dim3((EMB_D  / 64) * (N_TOTAL / 64)), 256, 0, stream>>>(W1T, W1, EMB_D,   N_TOTAL);
    transpose_convert<<<dim3((N_TOTAL / 64) * (N_TOTAL / 64)), 256, 0, stream>>>(U1T, U1, N_TOTAL, N_TOTAL);
    transpose_convert<<<dim3((N_TOTAL / 64) * (N_TOTAL / 64)), 256, 0, stream>>>(W2T, W2, N_TOTAL, N_TOTAL);
    transpose_convert<<<dim3((N_TOTAL / 64) * (N_TOTAL / 64)), 256, 0, stream>>>(U2T, U2, N_TOTAL, N_TOTAL);

    ew1_gemm<<<dim3((EW_ROWS / 128) * 8), 256, 0, stream>>>(EW1, embb, W1T);
    gather_xw1<<<dim3(64), 256, 0, stream>>>(ring[0], EW1, tokens, 0);

    ushort* h2c = h2a; ushort* h2n = h2b;
    for (int i = 0; i <= TSEQ; ++i) {
        ushort* sl_cur = ring[i % 3];
        const ushort* sl_prev = (i == 0) ? h1zero : ring[(i - 1) % 3];
        ushort* sl_next = ring[(i + 1) % 3];
        fused_step<<<dim3(512), 256, 0, stream>>>(
            EW1, tokens, sl_cur, sl_prev, sl_next,
            U1T, b1, W2T, U2T, b2, h2c, h2n, i);
        if (i >= 1) { ushort* t = h2c; h2c = h2n; h2n = t; }
    }

    out_kernel<<<dim3(M_TOTAL / 4), dim3(256), 0, stream>>>(out, h2c, Wo, bo);
}

// Round 14
// 2206.655 us; speedup vs baseline: 1.8317x; 1.0176x over previous
//
#include <hip/hip_runtime.h>
#include <math.h>

#define M_TOTAL 2048
#define N_TOTAL 1024
#define TSEQ    80
#define EMB_D   512
#define VOCAB   50000
#define EW_ROWS 50048            // VOCAB padded to 128
#define BK      64

typedef __attribute__((ext_vector_type(8))) short bf16x8;
typedef __attribute__((ext_vector_type(4))) float f32x4;

__device__ __forceinline__ ushort f2bf(float f) {
    union { float f; unsigned u; } v; v.f = f;
    unsigned r = v.u + 0x7FFFu + ((v.u >> 16) & 1u);
    return (ushort)(r >> 16);
}
__device__ __forceinline__ float bf2f(ushort h) {
    union { unsigned u; float f; } v; v.u = ((unsigned)h) << 16;
    return v.f;
}
__device__ __forceinline__ void gload_lds16(const ushort* g, ushort* l) {
    __builtin_amdgcn_global_load_lds(
        (const __attribute__((address_space(1))) void*)g,
        (__attribute__((address_space(3))) void*)l, 16, 0, 0);
}
#define VMC6()  asm volatile("s_waitcnt vmcnt(6)" ::: "memory")
#define VMC0()  asm volatile("s_waitcnt vmcnt(0)" ::: "memory")
#define VM0()   asm volatile("s_waitcnt vmcnt(0)" ::: "memory")
#define SBAR()  __builtin_amdgcn_s_barrier()
#define SCHED0() __builtin_amdgcn_sched_barrier(0)

// ---------------------------------------------------------------------------
// Fused per-step kernel — R13 core; xw1 slab+gather REMOVED. The L1 epilogue
// reads EW1[token[row][i]][col] directly (tokens pre-loaded before stage(0):
// they are the OLDEST loads in the vm queue, so the first vmcnt(6) drains
// them and the counted-wait arithmetic is unchanged).
// (4x2) hybrid XCD pinning: xcd = bid&7 = (mg<<1)|ng.
// Counted-vmcnt triple-buffered pipeline, 72 KB LDS -> 2 blocks/CU.
// layer = bid>>8: CU c holds bids {c, c+256} = one L1(16ch) + one L2(32ch).
//   L1 (bid<256):  h1[i]  = tanh(EW1[tok[:,i]] + h1[i-1]@U1 + b1)
//   L2 (bid>=256): h2[i-1]= tanh(h1[i-1]@W2 + h2[i-2]@U2 + b2)
// ---------------------------------------------------------------------------
__global__ __launch_bounds__(256) void fused_step(
    const ushort* __restrict__ EW1,
    const int* __restrict__ tok,
    ushort* __restrict__ h1cur,           // write: h1[i]
    const ushort* __restrict__ h1prev,    // read:  h1[i-1] (h1zero at i==0)
    const ushort* __restrict__ U1T, const float* __restrict__ b1,
    const ushort* __restrict__ W2T, const ushort* __restrict__ U2T,
    const float* __restrict__ b2,
    const ushort* __restrict__ h2c, ushort* __restrict__ h2n,
    int i)
{
    __shared__ ushort As[3][128 * BK];   // 48 KB
    __shared__ ushort Bs[3][64 * BK];    // 24 KB
    const int tid = threadIdx.x;
    const int w = tid >> 6, l = tid & 63;
    const int wr = w >> 1, wc = w & 1;        // wave grid 2x2, wave-tile 64x32
    const int bid = blockIdx.x;
    const int layer = bid >> 8;               // 0: bids 0..255, 1: 256..511
    const int xcd = bid & 7;                  // XCD under round-robin dispatch
    const int mg = xcd >> 1;                  // m-group 0..3 (A pinning x2)
    const int ng = xcd & 1;                   // n-group 0..1 (B pinning x4)
    const int idx = (bid >> 3) & 31;          // 0..31
    const int m = mg * 4 + (idx & 3);         // 0..15
    const int n = ng * 8 + (idx >> 2);        // 0..15
    const int bm0 = m << 7;
    const int bn0 = n << 6;

    if (layer == 0 && i >= TSEQ) return;      // i==80: L2 only
    if (layer == 1 && i < 1) return;          // i==0:  L1 only

    // ---- L1 token prologue: 16 raw token loads issued BEFORE stage(0);
    // consumed only in the epilogue (loads stay in flight through the loop).
    int tkv[16];
    if (layer == 0) {
        #pragma unroll
        for (int mf = 0; mf < 4; ++mf)
            #pragma unroll
            for (int rr = 0; rr < 4; ++rr) {
                const int row = bm0 + wr * 64 + mf * 16 + ((l >> 4) << 2) + rr;
                tkv[mf * 4 + rr] = tok[row * TSEQ + i];
            }
    }

    // staging thread-constants (XOR-pre-swizzled source granule)
    const int lr = l >> 3;
    const int se = ((l & 7) ^ lr) << 3;
    const size_t ga0 = (size_t)(bm0 + w * 32 + 0  + lr) * N_TOTAL + se;
    const size_t ga1 = (size_t)(bm0 + w * 32 + 8  + lr) * N_TOTAL + se;
    const size_t ga2 = (size_t)(bm0 + w * 32 + 16 + lr) * N_TOTAL + se;
    const size_t ga3 = (size_t)(bm0 + w * 32 + 24 + lr) * N_TOTAL + se;
    const size_t gb0 = (size_t)(bn0 + w * 16 + 0  + lr) * N_TOTAL + se;
    const size_t gb1 = (size_t)(bn0 + w * 16 + 8  + lr) * N_TOTAL + se;
    const int la0 = (w * 32 + 0)  * BK + l * 8;
    const int la1 = (w * 32 + 8)  * BK + l * 8;
    const int la2 = (w * 32 + 16) * BK + l * 8;
    const int la3 = (w * 32 + 24) * BK + l * 8;
    const int lb0 = (w * 16 + 0)  * BK + l * 8;
    const int lb1 = (w * 16 + 8)  * BK + l * 8;

    auto stage = [&](const ushort* __restrict__ A, const ushort* __restrict__ B,
                     int k0, int buf) {
        gload_lds16(A + ga0 + k0, &As[buf][la0]);
        gload_lds16(A + ga1 + k0, &As[buf][la1]);
        gload_lds16(A + ga2 + k0, &As[buf][la2]);
        gload_lds16(A + ga3 + k0, &As[buf][la3]);
        gload_lds16(B + gb0 + k0, &Bs[buf][lb0]);
        gload_lds16(B + gb1 + k0, &Bs[buf][lb1]);
    };

    f32x4 acc[4][2] = {};

    auto compute = [&](int buf) {
        __builtin_amdgcn_s_setprio(1);
        #pragma unroll
        for (int kf = 0; kf < 2; ++kf) {
            const int ke = kf * 32 + (l >> 4) * 8;
            bf16x8 a[4], b[2];
            #pragma unroll
            for (int mf = 0; mf < 4; ++mf) {
                const int row = wr * 64 + mf * 16 + (l & 15);
                a[mf] = *(const bf16x8*)&As[buf][row * BK + (ke ^ ((row & 7) << 3))];
            }
            #pragma unroll
            for (int nf = 0; nf < 2; ++nf) {
                const int row = wc * 32 + nf * 16 + (l & 15);
                b[nf] = *(const bf16x8*)&Bs[buf][row * BK + (ke ^ ((row & 7) << 3))];
            }
            #pragma unroll
            for (int mf = 0; mf < 4; ++mf)
                #pragma unroll
                for (int nf = 0; nf < 2; ++nf)
                    acc[mf][nf] = __builtin_amdgcn_mfma_f32_16x16x32_bf16(
                        a[mf], b[nf], acc[mf][nf], 0, 0, 0);
        }
        __builtin_amdgcn_s_setprio(0);
    };

    if (layer == 0) {
        auto stage_cc = [&](int cc, int buf) { stage(h1prev, U1T, cc << 6, buf); };
        stage_cc(0, 0);
        int bufc = 0;
        #pragma unroll
        for (int c = 0; c < 16; ++c) {
            int bufn = bufc + 1; if (bufn == 3) bufn = 0;
            if (c + 1 < 16) { stage_cc(c + 1, bufn); VMC6(); }
            else            { VMC0(); }
            SBAR(); SCHED0();
            compute(bufc);
            bufc = bufn;
        }
        #pragma unroll
        for (int nf = 0; nf < 2; ++nf) {
            const int col = bn0 + wc * 32 + nf * 16 + (l & 15);
            const float bz = b1[col];
            #pragma unroll
            for (int mf = 0; mf < 4; ++mf) {
                const int rb = bm0 + wr * 64 + mf * 16 + (l >> 4) * 4;
                #pragma unroll
                for (int rr = 0; rr < 4; ++rr) {
                    const unsigned ro = (unsigned)tkv[mf * 4 + rr] * N_TOTAL;
                    const float xw = bf2f(EW1[ro + col]);
                    h1cur[(size_t)(rb + rr) * N_TOTAL + col] =
                        f2bf(tanhf(acc[mf][nf][rr] + xw + bz));
                }
            }
        }
    } else {
        auto stage_cc = [&](int cc, int buf) {
            if (cc < 16) stage(h1prev, W2T, cc << 6, buf);
            else         stage(h2c,    U2T, (cc - 16) << 6, buf);
        };
        stage_cc(0, 0);
        int bufc = 0;
        #pragma unroll
        for (int c = 0; c < 32; ++c) {
            int bufn = bufc + 1; if (bufn == 3) bufn = 0;
            if (c + 1 < 32) { stage_cc(c + 1, bufn); VMC6(); }
            else            { VMC0(); }
            SBAR(); SCHED0();
            compute(bufc);
            bufc = bufn;
        }
        #pragma unroll
        for (int nf = 0; nf < 2; ++nf) {
            const int col = bn0 + wc * 32 + nf * 16 + (l & 15);
            const float bz = b2[col];
            #pragma unroll
            for (int mf = 0; mf < 4; ++mf) {
                const int rb = bm0 + wr * 64 + mf * 16 + (l >> 4) * 4;
                #pragma unroll
                for (int rr = 0; rr < 4; ++rr)
                    h2n[(size_t)(rb + rr) * N_TOTAL + col] =
                        f2bf(tanhf(acc[mf][nf][rr] + bz));
            }
        }
    }
}

// ---------------------------------------------------------------------------
// EW1[v][n] = embb[v] @ W1^T (one-time, M=50048 padded, K=512). 128x128 tile,
// 256 thr, 2-phase double-buffer (fill-BW-bound; measured ~100 us).
// ---------------------------------------------------------------------------
__global__ __launch_bounds__(256, 2) void ew1_gemm(
    ushort* __restrict__ EW1,
    const ushort* __restrict__ embb,     // [50000][512]
    const ushort* __restrict__ W1T)      // [1024][512]
{
    __shared__ ushort As[2][128 * BK];
    __shared__ ushort Bs[2][128 * BK];
    const int tid = threadIdx.x;
    const int w = tid >> 6, l = tid & 63;
    const int wr = w >> 1, wc = w & 1;
    const int bid = blockIdx.x;
    const int n = bid & 7, m = bid >> 3;        // m 0..390
    const int bm0 = m << 7, bn0 = n << 7;

    const int lr = l >> 3;
    const int se = ((l & 7) ^ lr) << 3;
    size_t ga[4], gb[4];
    #pragma unroll
    for (int j = 0; j < 4; ++j) {
        int row = bm0 + w * 32 + j * 8 + lr;
        if (row >= VOCAB) row = VOCAB - 1;      // clamp (results discarded)
        ga[j] = (size_t)row * EMB_D + se;
        gb[j] = (size_t)(bn0 + w * 32 + j * 8 + lr) * EMB_D + se;
    }

    auto stage = [&](int c, int buf) {
        const int k0 = c << 6;
        #pragma unroll
        for (int j = 0; j < 4; ++j)
            gload_lds16(embb + ga[j] + k0, &As[buf][(w * 32 + j * 8) * BK + l * 8]);
        #pragma unroll
        for (int j = 0; j < 4; ++j)
            gload_lds16(W1T + gb[j] + k0, &Bs[buf][(w * 32 + j * 8) * BK + l * 8]);
    };

    f32x4 acc[4][4] = {};
    stage(0, 0);
    VM0(); __syncthreads();
    #pragma unroll
    for (int c = 0; c < 8; ++c) {
        const int buf = c & 1;
        if (c + 1 < 8) stage(c + 1, buf ^ 1);
        #pragma unroll
        for (int kf = 0; kf < 2; ++kf) {
            const int ke = kf * 32 + (l >> 4) * 8;
            bf16x8 a[4], b[4];
            #pragma unroll
            for (int mf = 0; mf < 4; ++mf) {
                const int row = wr * 64 + mf * 16 + (l & 15);
                a[mf] = *(const bf16x8*)&As[buf][row * BK + (ke ^ ((row & 7) << 3))];
            }
            #pragma unroll
            for (int nf = 0; nf < 4; ++nf) {
                const int row = wc * 64 + nf * 16 + (l & 15);
                b[nf] = *(const bf16x8*)&Bs[buf][row * BK + (ke ^ ((row & 7) << 3))];
            }
            #pragma unroll
            for (int mf = 0; mf < 4; ++mf)
                #pragma unroll
                for (int nf = 0; nf < 4; ++nf)
                    acc[mf][nf] = __builtin_amdgcn_mfma_f32_16x16x32_bf16(
                        a[mf], b[nf], acc[mf][nf], 0, 0, 0);
        }
        VM0(); __syncthreads();
    }

    #pragma unroll
    for (int nf = 0; nf < 4; ++nf) {
        const int col = bn0 + wc * 64 + nf * 16 + (l & 15);
        #pragma unroll
        for (int mf = 0; mf < 4; ++mf) {
            const int rb = bm0 + wr * 64 + mf * 16 + (l >> 4) * 4;
            #pragma unroll
            for (int rr = 0; rr < 4; ++rr)
                if (rb + rr < VOCAB)
                    EW1[(size_t)(rb + rr) * N_TOTAL + col] = f2bf(acc[mf][nf][rr]);
        }
    }
}

// emb fp32 -> bf16 (50000*512/8/256 = 12500 blocks)
__global__ __launch_bounds__(256) void emb_convert(
    ushort* __restrict__ dst, const float* __restrict__ src)
{
    const size_t i = ((size_t)blockIdx.x * 256 + threadIdx.x) * 8;
    const float4 v0 = *(const float4*)(src + i);
    const float4 v1 = *(const float4*)(src + i + 4);
    const unsigned w0 = f2bf(v0.x) | (f2bf(v0.y) << 16);
    const unsigned w1 = f2bf(v0.z) | (f2bf(v0.w) << 16);
    const unsigned w2 = f2bf(v1.x) | (f2bf(v1.y) << 16);
    const unsigned w3 = f2bf(v1.z) | (f2bf(v1.w) << 16);
    *(uint4*)(dst + i) = make_uint4(w0, w1, w2, w3);
}

// W [K][N] fp32 -> WT [N][K] bf16
__global__ __launch_bounds__(256) void transpose_convert(
    ushort* __restrict__ outT, const float* __restrict__ in, int K, int N)
{
    __shared__ float tile[64][65];
    const int tiles_n = N >> 6;
    const int k0 = (blockIdx.x / tiles_n) << 6;
    const int n0 = (blockIdx.x % tiles_n) << 6;
    const int tid = threadIdx.x;
    const int r = tid >> 4, c = (tid & 15) << 2;
    #pragma unroll
    for (int i = 0; i < 4; ++i) {
        const float4 v = *(const float4*)(in + (size_t)(k0 + r + i * 16) * N + n0 + c);
        tile[r + i * 16][c + 0] = v.x;
        tile[r + i * 16][c + 1] = v.y;
        tile[r + i * 16][c + 2] = v.z;
        tile[r + i * 16][c + 3] = v.w;
    }
    __syncthreads();
    const int n = tid >> 2, ks = (tid & 3) << 4;
    unsigned pk[8];
    #pragma unroll
    for (int j = 0; j < 8; ++j) {
        const unsigned lo = f2bf(tile[ks + 2 * j][n]);
        const unsigned hi = f2bf(tile[ks + 2 * j + 1][n]);
        pk[j] = lo | (hi << 16);
    }
    ushort* dst = outT + (size_t)(n0 + n) * K + k0 + ks;
    *(uint4*)(dst + 0) = make_uint4(pk[0], pk[1], pk[2], pk[3]);
    *(uint4*)(dst + 8) = make_uint4(pk[4], pk[5], pk[6], pk[7]);
}

__global__ __launch_bounds__(256) void out_kernel(
    float* __restrict__ out, const ushort* __restrict__ h2,
    const float* __restrict__ Wo, const float* __restrict__ bo)
{
    const int row  = blockIdx.x * 4 + (threadIdx.x >> 6);
    const int lane = threadIdx.x & 63;
    const ushort* hr = h2 + (size_t)row * N_TOTAL;
    float s = 0.f;
    for (int k = lane; k < N_TOTAL; k += 64)
        s += bf2f(hr[k]) * Wo[k];
    #pragma unroll
    for (int off = 32; off; off >>= 1)
        s += __shfl_down(s, off);
    if (lane == 0)
        out[row] = 1.f / (1.f + expf(-(s + bo[0])));
}

extern "C" void kernel_launch(void* const* d_in, const int* in_sizes, int n_in,
                              void* d_out, int out_size, void* d_ws, size_t ws_size,
                              hipStream_t stream) {
    const int*   tokens = (const int*)  d_in[0];
    const float* emb    = (const float*)d_in[1];
    const float* W1     = (const float*)d_in[2];
    const float* U1     = (const float*)d_in[3];
    const float* b1     = (const float*)d_in[4];
    const float* W2     = (const float*)d_in[5];
    const float* U2     = (const float*)d_in[6];
    const float* b2     = (const float*)d_in[7];
    const float* Wo     = (const float*)d_in[8];
    const float* bo     = (const float*)d_in[9];
    float* out = (float*)d_out;

    char* ws = (char*)d_ws;
    const size_t HB = (size_t)M_TOTAL * N_TOTAL * sizeof(ushort);      // 4 MB
    size_t off = 0;
    ushort* h1zero = (ushort*)(ws + off); off += HB;
    ushort* h1a    = (ushort*)(ws + off); off += HB;
    ushort* h1b    = (ushort*)(ws + off); off += HB;
    ushort* h2a    = (ushort*)(ws + off); off += HB;
    ushort* h2b    = (ushort*)(ws + off); off += HB;
    ushort* W1T = (ushort*)(ws + off); off += (size_t)N_TOTAL * EMB_D   * 2;
    ushort* U1T = (ushort*)(ws + off); off += (size_t)N_TOTAL * N_TOTAL * 2;
    ushort* W2T = (ushort*)(ws + off); off += (size_t)N_TOTAL * N_TOTAL * 2;
    ushort* U2T = (ushort*)(ws + off); off += (size_t)N_TOTAL * N_TOTAL * 2;
    ushort* embb = (ushort*)(ws + off); off += (size_t)VOCAB * EMB_D * 2;
    ushort* EW1  = (ushort*)(ws + off); off += (size_t)EW_ROWS * N_TOTAL * 2;

    // h1zero: L1's A at i=0. h2a: L2's h2[-1] at i=1 (must be zero for
    // correctness AND replay determinism — ws is not re-poisoned).
    hipMemsetAsync(h1zero, 0, HB, stream);
    hipMemsetAsync(h2a,   0, HB, stream);

    emb_convert<<<dim3(12500), 256, 0, stream>>>(embb, emb);
    transpose_convert<<<dim3((EMB_D  / 64) * (N_TOTAL / 64)), 256, 0, stream>>>(W1T, W1, EMB_D,   N_TOTAL);
    transpose_convert<<<dim3((N_TOTAL / 64) * (N_TOTAL / 64)), 256, 0, stream>>>(U1T, U1, N_TOTAL, N_TOTAL);
    transpose_convert<<<dim3((N_TOTAL / 64) * (N_TOTAL / 64)), 256, 0, stream>>>(W2T, W2, N_TOTAL, N_TOTAL);
    transpose_convert<<<dim3((N_TOTAL / 64) * (N_TOTAL / 64)), 256, 0, stream>>>(U2T, U2, N_TOTAL, N_TOTAL);

    ew1_gemm<<<dim3((EW_ROWS / 128) * 8), 256, 0, stream>>>(EW1, embb, W1T);

    ushort* h1buf[2] = { h1a, h1b };
    ushort* h2c = h2a; ushort* h2n = h2b;
    for (int i = 0; i <= TSEQ; ++i) {
        ushort* h1cur = h1buf[i & 1];
        const ushort* h1prev = (i == 0) ? h1zero : h1buf[(i - 1) & 1];
        fused_step<<<dim3(512), 256, 0, stream>>>(
            EW1, tokens, h1cur, h1prev,
            U1T, b1, W2T, U2T, b2, h2c, h2n, i);
        if (i >= 1) { ushort* t = h2c; h2c = h2n; h2n = t; }
    }

    out_kernel<<<dim3(M_TOTAL / 4), dim3(256), 0, stream>>>(out, h2c, Wo, bo);
}

// Round 17
// 2204.376 us; speedup vs baseline: 1.8336x; 1.0010x over previous
//
#include <hip/hip_runtime.h>
#include <math.h>

#define M_TOTAL 2048
#define N_TOTAL 1024
#define TSEQ    80
#define EMB_D   512
#define VOCAB   50000
#define EW_ROWS 50048            // VOCAB padded to 128
#define BK      64

typedef __attribute__((ext_vector_type(8))) short bf16x8;
typedef __attribute__((ext_vector_type(4))) float f32x4;

__device__ __forceinline__ ushort f2bf(float f) {
    union { float f; unsigned u; } v; v.f = f;
    unsigned r = v.u + 0x7FFFu + ((v.u >> 16) & 1u);
    return (ushort)(r >> 16);
}
__device__ __forceinline__ float bf2f(ushort h) {
    union { unsigned u; float f; } v; v.u = ((unsigned)h) << 16;
    return v.f;
}
__device__ __forceinline__ void gload_lds16(const ushort* g, ushort* l) {
    __builtin_amdgcn_global_load_lds(
        (const __attribute__((address_space(1))) void*)g,
        (__attribute__((address_space(3))) void*)l, 16, 0, 0);
}
#define VMC6()  asm volatile("s_waitcnt vmcnt(6)" ::: "memory")
#define VMC0()  asm volatile("s_waitcnt vmcnt(0)" ::: "memory")
#define VM0()   asm volatile("s_waitcnt vmcnt(0)" ::: "memory")
#define SBAR()  __builtin_amdgcn_s_barrier()
#define SCHED0() __builtin_amdgcn_sched_barrier(0)

// ---------------------------------------------------------------------------
// Fused per-step kernel (R14, proven 2206 us). L1 epilogue reads
// EW1[token[row][i]][col] directly (tokens pre-loaded before stage(0):
// oldest loads in the vm queue, drained by the first vmcnt(6)).
// (4x2) hybrid XCD pinning: xcd = bid&7 = (mg<<1)|ng.
// Counted-vmcnt triple-buffered pipeline, 72 KB LDS -> 2 blocks/CU.
// layer = bid>>8: CU c holds bids {c, c+256} = one L1(16ch) + one L2(32ch).
//   L1 (bid<256):  h1[i]  = tanh(EW1[tok[:,i]] + h1[i-1]@U1 + b1)
//   L2 (bid>=256): h2[i-1]= tanh(h1[i-1]@W2 + h2[i-2]@U2 + b2)
// ---------------------------------------------------------------------------
__global__ __launch_bounds__(256) void fused_step(
    const ushort* __restrict__ EW1,
    const int* __restrict__ tok,
    ushort* __restrict__ h1cur,           // write: h1[i]
    const ushort* __restrict__ h1prev,    // read:  h1[i-1] (h1zero at i==0)
    const ushort* __restrict__ U1T, const float* __restrict__ b1,
    const ushort* __restrict__ W2T, const ushort* __restrict__ U2T,
    const float* __restrict__ b2,
    const ushort* __restrict__ h2c, ushort* __restrict__ h2n,
    int i)
{
    __shared__ ushort As[3][128 * BK];   // 48 KB
    __shared__ ushort Bs[3][64 * BK];    // 24 KB
    const int tid = threadIdx.x;
    const int w = tid >> 6, l = tid & 63;
    const int wr = w >> 1, wc = w & 1;        // wave grid 2x2, wave-tile 64x32
    const int bid = blockIdx.x;
    const int layer = bid >> 8;               // 0: bids 0..255, 1: 256..511
    const int xcd = bid & 7;                  // XCD under round-robin dispatch
    const int mg = xcd >> 1;                  // m-group 0..3 (A pinning x2)
    const int ng = xcd & 1;                   // n-group 0..1 (B pinning x4)
    const int idx = (bid >> 3) & 31;          // 0..31
    const int m = mg * 4 + (idx & 3);         // 0..15
    const int n = ng * 8 + (idx >> 2);        // 0..15
    const int bm0 = m << 7;
    const int bn0 = n << 6;

    if (layer == 0 && i >= TSEQ) return;      // i==80: L2 only
    if (layer == 1 && i < 1) return;          // i==0:  L1 only

    // ---- L1 token prologue: 16 raw token loads issued BEFORE stage(0);
    // consumed only in the epilogue (loads stay in flight through the loop).
    int tkv[16];
    if (layer == 0) {
        #pragma unroll
        for (int mf = 0; mf < 4; ++mf)
            #pragma unroll
            for (int rr = 0; rr < 4; ++rr) {
                const int row = bm0 + wr * 64 + mf * 16 + ((l >> 4) << 2) + rr;
                tkv[mf * 4 + rr] = tok[row * TSEQ + i];
            }
    }

    // staging thread-constants (XOR-pre-swizzled source granule)
    const int lr = l >> 3;
    const int se = ((l & 7) ^ lr) << 3;
    const size_t ga0 = (size_t)(bm0 + w * 32 + 0  + lr) * N_TOTAL + se;
    const size_t ga1 = (size_t)(bm0 + w * 32 + 8  + lr) * N_TOTAL + se;
    const size_t ga2 = (size_t)(bm0 + w * 32 + 16 + lr) * N_TOTAL + se;
    const size_t ga3 = (size_t)(bm0 + w * 32 + 24 + lr) * N_TOTAL + se;
    const size_t gb0 = (size_t)(bn0 + w * 16 + 0  + lr) * N_TOTAL + se;
    const size_t gb1 = (size_t)(bn0 + w * 16 + 8  + lr) * N_TOTAL + se;
    const int la0 = (w * 32 + 0)  * BK + l * 8;
    const int la1 = (w * 32 + 8)  * BK + l * 8;
    const int la2 = (w * 32 + 16) * BK + l * 8;
    const int la3 = (w * 32 + 24) * BK + l * 8;
    const int lb0 = (w * 16 + 0)  * BK + l * 8;
    const int lb1 = (w * 16 + 8)  * BK + l * 8;

    auto stage = [&](const ushort* __restrict__ A, const ushort* __restrict__ B,
                     int k0, int buf) {
        gload_lds16(A + ga0 + k0, &As[buf][la0]);
        gload_lds16(A + ga1 + k0, &As[buf][la1]);
        gload_lds16(A + ga2 + k0, &As[buf][la2]);
        gload_lds16(A + ga3 + k0, &As[buf][la3]);
        gload_lds16(B + gb0 + k0, &Bs[buf][lb0]);
        gload_lds16(B + gb1 + k0, &Bs[buf][lb1]);
    };

    f32x4 acc[4][2] = {};

    auto compute = [&](int buf) {
        __builtin_amdgcn_s_setprio(1);
        #pragma unroll
        for (int kf = 0; kf < 2; ++kf) {
            const int ke = kf * 32 + (l >> 4) * 8;
            bf16x8 a[4], b[2];
            #pragma unroll
            for (int mf = 0; mf < 4; ++mf) {
                const int row = wr * 64 + mf * 16 + (l & 15);
                a[mf] = *(const bf16x8*)&As[buf][row * BK + (ke ^ ((row & 7) << 3))];
            }
            #pragma unroll
            for (int nf = 0; nf < 2; ++nf) {
                const int row = wc * 32 + nf * 16 + (l & 15);
                b[nf] = *(const bf16x8*)&Bs[buf][row * BK + (ke ^ ((row & 7) << 3))];
            }
            #pragma unroll
            for (int mf = 0; mf < 4; ++mf)
                #pragma unroll
                for (int nf = 0; nf < 2; ++nf)
                    acc[mf][nf] = __builtin_amdgcn_mfma_f32_16x16x32_bf16(
                        a[mf], b[nf], acc[mf][nf], 0, 0, 0);
        }
        __builtin_amdgcn_s_setprio(0);
    };

    if (layer == 0) {
        stage(h1prev, U1T, 0, 0);
        int bufc = 0;
        #pragma unroll
        for (int c = 0; c < 16; ++c) {
            int bufn = bufc + 1; if (bufn == 3) bufn = 0;
            if (c + 1 < 16) { stage(h1prev, U1T, (c + 1) << 6, bufn); VMC6(); }
            else            { VMC0(); }
            SBAR(); SCHED0();
            compute(bufc);
            bufc = bufn;
        }
        #pragma unroll
        for (int nf = 0; nf < 2; ++nf) {
            const int col = bn0 + wc * 32 + nf * 16 + (l & 15);
            const float bz = b1[col];
            #pragma unroll
            for (int mf = 0; mf < 4; ++mf) {
                const int rb = bm0 + wr * 64 + mf * 16 + (l >> 4) * 4;
                #pragma unroll
                for (int rr = 0; rr < 4; ++rr) {
                    const unsigned ro = (unsigned)tkv[mf * 4 + rr] * N_TOTAL;
                    const float xw = bf2f(EW1[ro + col]);
                    h1cur[(size_t)(rb + rr) * N_TOTAL + col] =
                        f2bf(tanhf(acc[mf][nf][rr] + xw + bz));
                }
            }
        }
    } else {
        stage(h1prev, W2T, 0, 0);
        int bufc = 0;
        #pragma unroll
        for (int c = 0; c < 32; ++c) {
            int bufn = bufc + 1; if (bufn == 3) bufn = 0;
            if (c + 1 < 32) {
                if (c + 1 < 16) stage(h1prev, W2T, (c + 1) << 6, bufn);
                else            stage(h2c,    U2T, (c + 1 - 16) << 6, bufn);
                VMC6();
            } else { VMC0(); }
            SBAR(); SCHED0();
            compute(bufc);
            bufc = bufn;
        }
        #pragma unroll
        for (int nf = 0; nf < 2; ++nf) {
            const int col = bn0 + wc * 32 + nf * 16 + (l & 15);
            const float bz = b2[col];
            #pragma unroll
            for (int mf = 0; mf < 4; ++mf) {
                const int rb = bm0 + wr * 64 + mf * 16 + (l >> 4) * 4;
                #pragma unroll
                for (int rr = 0; rr < 4; ++rr)
                    h2n[(size_t)(rb + rr) * N_TOTAL + col] =
                        f2bf(tanhf(acc[mf][nf][rr] + bz));
            }
        }
    }
}

// ---------------------------------------------------------------------------
// EW1[v][n] = embb[v] @ W1^T (one-time, M=50048 padded, K=512). 128x128 tile,
// 256 thr, 2-phase double-buffer (fill-BW-bound; measured ~99 us).
// ---------------------------------------------------------------------------
__global__ __launch_bounds__(256, 2) void ew1_gemm(
    ushort* __restrict__ EW1,
    const ushort* __restrict__ embb,     // [50000][512]
    const ushort* __restrict__ W1T)      // [1024][512]
{
    __shared__ ushort As[2][128 * BK];
    __shared__ ushort Bs[2][128 * BK];
    const int tid = threadIdx.x;
    const int w = tid >> 6, l = tid & 63;
    const int wr = w >> 1, wc = w & 1;
    const int bid = blockIdx.x;
    const int n = bid & 7, m = bid >> 3;        // m 0..390
    const int bm0 = m << 7, bn0 = n << 7;

    const int lr = l >> 3;
    const int se = ((l & 7) ^ lr) << 3;
    size_t ga[4], gb[4];
    #pragma unroll
    for (int j = 0; j < 4; ++j) {
        int row = bm0 + w * 32 + j * 8 + lr;
        if (row >= VOCAB) row = VOCAB - 1;      // clamp (results discarded)
        ga[j] = (size_t)row * EMB_D + se;
        gb[j] = (size_t)(bn0 + w * 32 + j * 8 + lr) * EMB_D + se;
    }

    auto stage = [&](int c, int buf) {
        const int k0 = c << 6;
        #pragma unroll
        for (int j = 0; j < 4; ++j)
            gload_lds16(embb + ga[j] + k0, &As[buf][(w * 32 + j * 8) * BK + l * 8]);
        #pragma unroll
        for (int j = 0; j < 4; ++j)
            gload_lds16(W1T + gb[j] + k0, &Bs[buf][(w * 32 + j * 8) * BK + l * 8]);
    };

    f32x4 acc[4][4] = {};
    stage(0, 0);
    VM0(); __syncthreads();
    #pragma unroll
    for (int c = 0; c < 8; ++c) {
        const int buf = c & 1;
        if (c + 1 < 8) stage(c + 1, buf ^ 1);
        #pragma unroll
        for (int kf = 0; kf < 2; ++kf) {
            const int ke = kf * 32 + (l >> 4) * 8;
            bf16x8 a[4], b[4];
            #pragma unroll
            for (int mf = 0; mf < 4; ++mf) {
                const int row = wr * 64 + mf * 16 + (l & 15);
                a[mf] = *(const bf16x8*)&As[buf][row * BK + (ke ^ ((row & 7) << 3))];
            }
            #pragma unroll
            for (int nf = 0; nf < 4; ++nf) {
                const int row = wc * 64 + nf * 16 + (l & 15);
                b[nf] = *(const bf16x8*)&Bs[buf][row * BK + (ke ^ ((row & 7) << 3))];
            }
            #pragma unroll
            for (int mf = 0; mf < 4; ++mf)
                #pragma unroll
                for (int nf = 0; nf < 4; ++nf)
                    acc[mf][nf] = __builtin_amdgcn_mfma_f32_16x16x32_bf16(
                        a[mf], b[nf], acc[mf][nf], 0, 0, 0);
        }
        VM0(); __syncthreads();
    }

    #pragma unroll
    for (int nf = 0; nf < 4; ++nf) {
        const int col = bn0 + wc * 64 + nf * 16 + (l & 15);
        #pragma unroll
        for (int mf = 0; mf < 4; ++mf) {
            const int rb = bm0 + wr * 64 + mf * 16 + (l >> 4) * 4;
            #pragma unroll
            for (int rr = 0; rr < 4; ++rr)
                if (rb + rr < VOCAB)
                    EW1[(size_t)(rb + rr) * N_TOTAL + col] = f2bf(acc[mf][nf][rr]);
        }
    }
}

// emb fp32 -> bf16 (50000*512/8/256 = 12500 blocks)
__global__ __launch_bounds__(256) void emb_convert(
    ushort* __restrict__ dst, const float* __restrict__ src)
{
    const size_t i = ((size_t)blockIdx.x * 256 + threadIdx.x) * 8;
    const float4 v0 = *(const float4*)(src + i);
    const float4 v1 = *(const float4*)(src + i + 4);
    const unsigned w0 = f2bf(v0.x) | (f2bf(v0.y) << 16);
    const unsigned w1 = f2bf(v0.z) | (f2bf(v0.w) << 16);
    const unsigned w2 = f2bf(v1.x) | (f2bf(v1.y) << 16);
    const unsigned w3 = f2bf(v1.z) | (f2bf(v1.w) << 16);
    *(uint4*)(dst + i) = make_uint4(w0, w1, w2, w3);
}

// W [K][N] fp32 -> WT [N][K] bf16
__global__ __launch_bounds__(256) void transpose_convert(
    ushort* __restrict__ outT, const float* __restrict__ in, int K, int N)
{
    __shared__ float tile[64][65];
    const int tiles_n = N >> 6;
    const int k0 = (blockIdx.x / tiles_n) << 6;
    const int n0 = (blockIdx.x % tiles_n) << 6;
    const int tid = threadIdx.x;
    const int r = tid >> 4, c = (tid & 15) << 2;
    #pragma unroll
    for (int i = 0; i < 4; ++i) {
        const float4 v = *(const float4*)(in + (size_t)(k0 + r + i * 16) * N + n0 + c);
        tile[r + i * 16][c + 0] = v.x;
        tile[r + i * 16][c + 1] = v.y;
        tile[r + i * 16][c + 2] = v.z;
        tile[r + i * 16][c + 3] = v.w;
    }
    __syncthreads();
    const int n = tid >> 2, ks = (tid & 3) << 4;
    unsigned pk[8];
    #pragma unroll
    for (int j = 0; j < 8; ++j) {
        const unsigned lo = f2bf(tile[ks + 2 * j][n]);
        const unsigned hi = f2bf(tile[ks + 2 * j + 1][n]);
        pk[j] = lo | (hi << 16);
    }
    ushort* dst = outT + (size_t)(n0 + n) * K + k0 + ks;
    *(uint4*)(dst + 0) = make_uint4(pk[0], pk[1], pk[2], pk[3]);
    *(uint4*)(dst + 8) = make_uint4(pk[4], pk[5], pk[6], pk[7]);
}

__global__ __launch_bounds__(256) void out_kernel(
    float* __restrict__ out, const ushort* __restrict__ h2,
    const float* __restrict__ Wo, const float* __restrict__ bo)
{
    const int row  = blockIdx.x * 4 + (threadIdx.x >> 6);
    const int lane = threadIdx.x & 63;
    const ushort* hr = h2 + (size_t)row * N_TOTAL;
    float s = 0.f;
    for (int k = lane; k < N_TOTAL; k += 64)
        s += bf2f(hr[k]) * Wo[k];
    #pragma unroll
    for (int off = 32; off; off >>= 1)
        s += __shfl_down(s, off);
    if (lane == 0)
        out[row] = 1.f / (1.f + expf(-(s + bo[0])));
}

extern "C" void kernel_launch(void* const* d_in, const int* in_sizes, int n_in,
                              void* d_out, int out_size, void* d_ws, size_t ws_size,
                              hipStream_t stream) {
    const int*   tokens = (const int*)  d_in[0];
    const float* emb    = (const float*)d_in[1];
    const float* W1     = (const float*)d_in[2];
    const float* U1     = (const float*)d_in[3];
    const float* b1     = (const float*)d_in[4];
    const float* W2     = (const float*)d_in[5];
    const float* U2     = (const float*)d_in[6];
    const float* b2     = (const float*)d_in[7];
    const float* Wo     = (const float*)d_in[8];
    const float* bo     = (const float*)d_in[9];
    float* out = (float*)d_out;

    char* ws = (char*)d_ws;
    const size_t HB = (size_t)M_TOTAL * N_TOTAL * sizeof(ushort);      // 4 MB
    size_t off = 0;
    ushort* h1zero = (ushort*)(ws + off); off += HB;
    ushort* h1a    = (ushort*)(ws + off); off += HB;
    ushort* h1b    = (ushort*)(ws + off); off += HB;
    ushort* h2a    = (ushort*)(ws + off); off += HB;
    ushort* h2b    = (ushort*)(ws + off); off += HB;
    ushort* W1T = (ushort*)(ws + off); off += (size_t)N_TOTAL * EMB_D   * 2;
    ushort* U1T = (ushort*)(ws + off); off += (size_t)N_TOTAL * N_TOTAL * 2;
    ushort* W2T = (ushort*)(ws + off); off += (size_t)N_TOTAL * N_TOTAL * 2;
    ushort* U2T = (ushort*)(ws + off); off += (size_t)N_TOTAL * N_TOTAL * 2;
    ushort* embb = (ushort*)(ws + off); off += (size_t)VOCAB * EMB_D * 2;
    ushort* EW1  = (ushort*)(ws + off); off += (size_t)EW_ROWS * N_TOTAL * 2;

    // h1zero: L1's A at i=0. h2a: L2's h2[-1] source at i=1 (must be zeroed
    // every call — ws is not re-poisoned between timed replays).
    hipMemsetAsync(h1zero, 0, HB, stream);
    hipMemsetAsync(h2a,   0, HB, stream);

    emb_convert<<<dim3(12500), 256, 0, stream>>>(embb, emb);
    transpose_convert<<<dim3((EMB_D  / 64) * (N_TOTAL / 64)), 256, 0, stream>>>(W1T, W1, EMB_D,   N_TOTAL);
    transpose_convert<<<dim3((N_TOTAL / 64) * (N_TOTAL / 64)), 256, 0, stream>>>(U1T, U1, N_TOTAL, N_TOTAL);
    transpose_convert<<<dim3((N_TOTAL / 64) * (N_TOTAL / 64)), 256, 0, stream>>>(W2T, W2, N_TOTAL, N_TOTAL);
    transpose_convert<<<dim3((N_TOTAL / 64) * (N_TOTAL / 64)), 256, 0, stream>>>(U2T, U2, N_TOTAL, N_TOTAL);

    ew1_gemm<<<dim3((EW_ROWS / 128) * 8), 256, 0, stream>>>(EW1, embb, W1T);

    ushort* h1buf[2] = { h1a, h1b };
    ushort* h2c = h2a; ushort* h2n = h2b;
    for (int i = 0; i <= TSEQ; ++i) {
        ushort* h1cur = h1buf[i & 1];
        const ushort* h1prev = (i == 0) ? h1zero : h1buf[(i - 1) & 1];
        fused_step<<<dim3(512), 256, 0, stream>>>(
            EW1, tokens, h1cur, h1prev,
            U1T, b1, W2T, U2T, b2, h2c, h2n, i);
        if (i >= 1) { ushort* t = h2c; h2c = h2n; h2n = t; }
    }

    out_kernel<<<dim3(M_TOTAL / 4), dim3(256), 0, stream>>>(out, h2c, Wo, bo);
}